// Round 1
// baseline (11320.154 us; speedup 1.0000x reference)
//
#include <hip/hip_runtime.h>
#include <math.h>

#define BATCH 8
#define C 64
#define NH 8
#define HD 8
#define LTXT 77
#define H0 64
#define W0 64
#define HW0 (H0*W0)

// ---------------- text projection: tf[b,l,c] = th[b,l,:] . proj_w[c,:] + proj_b[c]
// grid: B*L blocks, 64 threads (c)
__global__ void text_proj_kernel(const float* __restrict__ th, const float* __restrict__ pw,
                                 const float* __restrict__ pb, float* __restrict__ tf) {
    __shared__ float sh[512];
    int bl = blockIdx.x;
    int c = threadIdx.x;
    const float* row = th + (size_t)bl * 512;
    for (int i = c; i < 512; i += 64) sh[i] = row[i];
    __syncthreads();
    const float* wrow = pw + c * 512;
    float acc = pb[c];
    for (int i = 0; i < 512; i += 4) {
        acc += sh[i] * wrow[i] + sh[i+1] * wrow[i+1] + sh[i+2] * wrow[i+2] + sh[i+3] * wrow[i+3];
    }
    tf[bl * 64 + c] = acc;
}

// ---------------- first 3x3 conv: x[8,3,64,64] -> feat[8,64,64,64], SAME pad
__global__ void conv_in_kernel(const float* __restrict__ x, const float* __restrict__ w,
                               const float* __restrict__ bias, float* __restrict__ feat) {
    int idx = blockIdx.x * blockDim.x + threadIdx.x;
    if (idx >= BATCH * C * HW0) return;
    int wx = idx & 63;
    int h = (idx >> 6) & 63;
    int o = (idx >> 12) & 63;
    int b = idx >> 18;
    const float* wr = w + o * 27;
    float acc = bias[o];
    for (int ci = 0; ci < 3; ci++) {
        for (int ky = 0; ky < 3; ky++) {
            int y = h + ky - 1;
            if ((unsigned)y >= 64u) continue;
            const float* xr = x + (((size_t)b * 3 + ci) * 64 + y) * 64;
            const float* wk = wr + ci * 9 + ky * 3;
            if (wx > 0) acc += xr[wx - 1] * wk[0];
            acc += xr[wx] * wk[1];
            if (wx < 63) acc += xr[wx + 1] * wk[2];
        }
    }
    feat[idx] = acc;
}

// ---------------- per-block K/V: k=LN(tf@kw^T+kb), v=tf@vw^T+vb
// grid: B*L blocks, 64 threads (one wave)
__global__ void kv_kernel(const float* __restrict__ tf,
                          const float* __restrict__ kw, const float* __restrict__ kb,
                          const float* __restrict__ vw, const float* __restrict__ vb,
                          const float* __restrict__ l2w, const float* __restrict__ l2b,
                          float* __restrict__ kbuf, float* __restrict__ vbuf) {
    __shared__ float sh[64];
    int bl = blockIdx.x;
    int o = threadIdx.x;
    sh[o] = tf[bl * 64 + o];
    __syncthreads();
    const float* kr = kw + o * 64;
    const float* vr = vw + o * 64;
    float ka = kb[o], va = vb[o];
    for (int c2 = 0; c2 < 64; c2++) {
        float t = sh[c2];
        ka += t * kr[c2];
        va += t * vr[c2];
    }
    // layernorm over the 64 lanes (block == one wave)
    float s = ka;
    for (int off = 32; off; off >>= 1) s += __shfl_xor(s, off, 64);
    float mean = s * (1.0f / 64.0f);
    float d = ka - mean;
    float s2 = d * d;
    for (int off = 32; off; off >>= 1) s2 += __shfl_xor(s2, off, 64);
    float rstd = rsqrtf(s2 * (1.0f / 64.0f) + 1e-5f);
    kbuf[bl * 64 + o] = d * rstd * l2w[o] + l2b[o];
    vbuf[bl * 64 + o] = va;
}

// ---------------- fused per-block attention: qproj + pe + LN + attn + outproj + residual
// grid: B * (HW0/64) blocks of 64 threads; one thread = one pixel
__global__ void __launch_bounds__(64)
attn_kernel(float* __restrict__ feat,
            const float* __restrict__ kbuf, const float* __restrict__ vbuf,
            const float* __restrict__ qw, const float* __restrict__ qb,
            const float* __restrict__ ow, const float* __restrict__ ob,
            const float* __restrict__ l1w, const float* __restrict__ l1b) {
    int b = blockIdx.x >> 6;
    int n = ((blockIdx.x & 63) << 6) | threadIdx.x;
    float* fcol = feat + (size_t)b * 64 * HW0 + n;

    float f[64];
#pragma unroll
    for (int c = 0; c < 64; c++) f[c] = fcol[c * HW0];

    // q projection
    float q[64];
#pragma unroll
    for (int o = 0; o < 64; o++) {
        const float4* wr = (const float4*)(qw + o * 64);
        float acc = qb[o];
#pragma unroll
        for (int i = 0; i < 16; i++) {
            float4 w4 = wr[i];
            acc += w4.x * f[4*i] + w4.y * f[4*i+1] + w4.z * f[4*i+2] + w4.w * f[4*i+3];
        }
        q[o] = acc;
    }

    // positional encoding: first 32 ch = x pos, next 32 = y pos, scaled 0.05
    float px = (float)(n & 63) * (1.0f / 63.0f);
    float py = (float)(n >> 6) * (1.0f / 63.0f);
#pragma unroll
    for (int c = 0; c < 64; c++) q[c] += 0.05f * (c < 32 ? px : py);

    // layernorm over channels
    float s = 0.f;
#pragma unroll
    for (int c = 0; c < 64; c++) s += q[c];
    float mean = s * (1.0f / 64.0f);
    float v = 0.f;
#pragma unroll
    for (int c = 0; c < 64; c++) { float d = q[c] - mean; v += d * d; }
    float rstd = rsqrtf(v * (1.0f / 64.0f) + 1e-5f);
#pragma unroll
    for (int c = 0; c < 64; c++) q[c] = (q[c] - mean) * rstd * l1w[c] + l1b[c];

    // cross attention, online softmax per head
    const float* kb_b = kbuf + b * LTXT * 64;
    const float* vb_b = vbuf + b * LTXT * 64;
    const float scale = 0.35355339059327373f;
    float out[64];
#pragma unroll
    for (int h8 = 0; h8 < NH; h8++) {
        float m = -1e30f, ssum = 0.f;
        float acc[8] = {0.f,0.f,0.f,0.f,0.f,0.f,0.f,0.f};
        for (int l = 0; l < LTXT; l++) {
            const float* kr = kb_b + l * 64 + h8 * 8;
            float sd = 0.f;
#pragma unroll
            for (int d = 0; d < 8; d++) sd += q[h8 * 8 + d] * kr[d];
            sd *= scale;
            float mn = fmaxf(m, sd);
            float cf = __expf(m - mn);
            float e = __expf(sd - mn);
            ssum = ssum * cf + e;
            const float* vr = vb_b + l * 64 + h8 * 8;
#pragma unroll
            for (int d = 0; d < 8; d++) acc[d] = acc[d] * cf + e * vr[d];
            m = mn;
        }
        float inv = 1.0f / ssum;
#pragma unroll
        for (int d = 0; d < 8; d++) out[h8 * 8 + d] = acc[d] * inv;
    }

    // out projection + residual (in place; each pixel column owned by one thread)
#pragma unroll
    for (int o = 0; o < 64; o++) {
        const float4* wr = (const float4*)(ow + o * 64);
        float acc = ob[o];
#pragma unroll
        for (int i = 0; i < 16; i++) {
            float4 w4 = wr[i];
            acc += w4.x * out[4*i] + w4.y * out[4*i+1] + w4.z * out[4*i+2] + w4.w * out[4*i+3];
        }
        fcol[o * HW0] += acc;
    }
}

// ---------------- upsample conv 3x3 (Cin=64 -> Cout=256) + pixel shuffle r=2 + relu
__global__ void up_conv_kernel(const float* __restrict__ in, const float* __restrict__ w,
                               const float* __restrict__ bias, float* __restrict__ out,
                               int Hin, int Win) {
    int idx = blockIdx.x * blockDim.x + threadIdx.x;
    int total = BATCH * 256 * Hin * Win;
    if (idx >= total) return;
    int wx = idx % Win;
    int t = idx / Win;
    int h = t % Hin; t /= Hin;
    int co = t % 256;
    int b = t / 256;
    const float* wr = w + co * 576; // 64*9
    float acc = bias[co];
    for (int ci = 0; ci < 64; ci++) {
        const float* base = in + (((size_t)b * 64 + ci) * Hin) * Win;
        const float* wk = wr + ci * 9;
#pragma unroll
        for (int ky = 0; ky < 3; ky++) {
            int y = h + ky - 1;
            if ((unsigned)y >= (unsigned)Hin) continue;
            const float* xr = base + y * Win;
            float a0 = (wx > 0) ? xr[wx - 1] : 0.f;
            float a1 = xr[wx];
            float a2 = (wx < Win - 1) ? xr[wx + 1] : 0.f;
            acc += a0 * wk[ky * 3 + 0] + a1 * wk[ky * 3 + 1] + a2 * wk[ky * 3 + 2];
        }
    }
    acc = fmaxf(acc, 0.f);
    int c = co >> 2, r1 = (co >> 1) & 1, r2 = co & 1;
    int Ho = Hin * 2, Wo = Win * 2;
    out[(((size_t)b * 64 + c) * Ho + (2 * h + r1)) * Wo + (2 * wx + r2)] = acc;
}

// ---------------- final 3x3 conv: [8,64,256,256] -> [8,3,256,256]
__global__ void final_conv_kernel(const float* __restrict__ in, const float* __restrict__ w,
                                  const float* __restrict__ bias, float* __restrict__ out) {
    int idx = blockIdx.x * blockDim.x + threadIdx.x;
    if (idx >= BATCH * 3 * 256 * 256) return;
    int wx = idx & 255;
    int h = (idx >> 8) & 255;
    int rem = idx >> 16;
    int co = rem % 3;
    int b = rem / 3;
    const float* wr = w + co * 576;
    float acc = bias[co];
    for (int ci = 0; ci < 64; ci++) {
        const float* base = in + (((size_t)b * 64 + ci) * 256) * 256;
        const float* wk = wr + ci * 9;
#pragma unroll
        for (int ky = 0; ky < 3; ky++) {
            int y = h + ky - 1;
            if ((unsigned)y >= 256u) continue;
            const float* xr = base + y * 256;
            float a0 = (wx > 0) ? xr[wx - 1] : 0.f;
            float a1 = xr[wx];
            float a2 = (wx < 255) ? xr[wx + 1] : 0.f;
            acc += a0 * wk[ky * 3 + 0] + a1 * wk[ky * 3 + 1] + a2 * wk[ky * 3 + 2];
        }
    }
    out[idx] = acc;
}

extern "C" void kernel_launch(void* const* d_in, const int* in_sizes, int n_in,
                              void* d_out, int out_size, void* d_ws, size_t ws_size,
                              hipStream_t stream) {
    const float* x      = (const float*)d_in[0];
    const float* th     = (const float*)d_in[1];
    const float* proj_w = (const float*)d_in[2];
    const float* proj_b = (const float*)d_in[3];
    const float* cf_w   = (const float*)d_in[4];
    const float* cf_b   = (const float*)d_in[5];
    const float* qw     = (const float*)d_in[6];
    const float* qb     = (const float*)d_in[7];
    const float* kw     = (const float*)d_in[8];
    const float* kb     = (const float*)d_in[9];
    const float* vw     = (const float*)d_in[10];
    const float* vb     = (const float*)d_in[11];
    const float* ow     = (const float*)d_in[12];
    const float* ob     = (const float*)d_in[13];
    const float* l1w    = (const float*)d_in[14];
    const float* l1b    = (const float*)d_in[15];
    const float* l2w    = (const float*)d_in[16];
    const float* l2b    = (const float*)d_in[17];
    const float* up_w   = (const float*)d_in[18];
    const float* up_b   = (const float*)d_in[19];
    const float* cl_w   = (const float*)d_in[20];
    const float* cl_b   = (const float*)d_in[21];

    float* ws   = (float*)d_ws;
    float* feat = ws;                      // 8*64*4096   = 2,097,152
    float* tf   = feat + 2097152;          // 8*77*64     = 39,424
    float* kbuf = tf + 39424;              // 39,424
    float* vbuf = kbuf + 39424;            // 39,424
    float* up1  = vbuf + 39424;            // 8*64*128*128 = 8,388,608
    float* up2  = up1 + 8388608;           // 8*64*256*256 = 33,554,432

    hipLaunchKernelGGL(text_proj_kernel, dim3(BATCH * LTXT), dim3(64), 0, stream,
                       th, proj_w, proj_b, tf);
    hipLaunchKernelGGL(conv_in_kernel, dim3((BATCH * C * HW0) / 256), dim3(256), 0, stream,
                       x, cf_w, cf_b, feat);

    for (int i = 0; i < 16; i++) {
        hipLaunchKernelGGL(kv_kernel, dim3(BATCH * LTXT), dim3(64), 0, stream,
                           tf, kw + i * 4096, kb + i * 64, vw + i * 4096, vb + i * 64,
                           l2w + i * 64, l2b + i * 64, kbuf, vbuf);
        hipLaunchKernelGGL(attn_kernel, dim3(BATCH * (HW0 / 64)), dim3(64), 0, stream,
                           feat, kbuf, vbuf, qw + i * 4096, qb + i * 64,
                           ow + i * 4096, ob + i * 64, l1w + i * 64, l1b + i * 64);
    }

    hipLaunchKernelGGL(up_conv_kernel, dim3((BATCH * 256 * 64 * 64) / 256), dim3(256), 0, stream,
                       feat, up_w, up_b, up1, 64, 64);
    hipLaunchKernelGGL(up_conv_kernel, dim3((BATCH * 256 * 128 * 128) / 256), dim3(256), 0, stream,
                       up1, up_w + 256 * 576, up_b + 256, up2, 128, 128);
    hipLaunchKernelGGL(final_conv_kernel, dim3((BATCH * 3 * 256 * 256) / 256), dim3(256), 0, stream,
                       up2, cl_w, cl_b, (float*)d_out);
}

// Round 2
// 2489.791 us; speedup vs baseline: 4.5466x; 4.5466x over previous
//
#include <hip/hip_runtime.h>
#include <math.h>

#define BATCH 8
#define C 64
#define NH 8
#define HD 8
#define LTXT 77
#define H0 64
#define W0 64
#define HW0 (H0*W0)

// ---------------- text projection: tf[b,l,c] = th[b,l,:] . proj_w[c,:] + proj_b[c]
__global__ void text_proj_kernel(const float* __restrict__ th, const float* __restrict__ pw,
                                 const float* __restrict__ pb, float* __restrict__ tf) {
    __shared__ float sh[512];
    int bl = blockIdx.x;
    int c = threadIdx.x;
    const float* row = th + (size_t)bl * 512;
    for (int i = c; i < 512; i += 64) sh[i] = row[i];
    __syncthreads();
    const float* wrow = pw + c * 512;
    float acc = pb[c];
    for (int i = 0; i < 512; i += 4) {
        acc += sh[i] * wrow[i] + sh[i+1] * wrow[i+1] + sh[i+2] * wrow[i+2] + sh[i+3] * wrow[i+3];
    }
    tf[bl * 64 + c] = acc;
}

// ---------------- first 3x3 conv: x[8,3,64,64] -> feat[8,64,64,64], SAME pad
__global__ void conv_in_kernel(const float* __restrict__ x, const float* __restrict__ w,
                               const float* __restrict__ bias, float* __restrict__ feat) {
    int idx = blockIdx.x * blockDim.x + threadIdx.x;
    if (idx >= BATCH * C * HW0) return;
    int wx = idx & 63;
    int h = (idx >> 6) & 63;
    int o = (idx >> 12) & 63;
    int b = idx >> 18;
    const float* wr = w + o * 27;
    float acc = bias[o];
    for (int ci = 0; ci < 3; ci++) {
        for (int ky = 0; ky < 3; ky++) {
            int y = h + ky - 1;
            if ((unsigned)y >= 64u) continue;
            const float* xr = x + (((size_t)b * 3 + ci) * 64 + y) * 64;
            const float* wk = wr + ci * 9 + ky * 3;
            if (wx > 0) acc += xr[wx - 1] * wk[0];
            acc += xr[wx] * wk[1];
            if (wx < 63) acc += xr[wx + 1] * wk[2];
        }
    }
    feat[idx] = acc;
}

// ---------------- K/V for ALL 16 blocks upfront: k=LN(tf@kw^T+kb), v=tf@vw^T+vb
// grid: 16*B*L blocks of 64 threads
__global__ void kv_all_kernel(const float* __restrict__ tf,
                              const float* __restrict__ kw, const float* __restrict__ kb,
                              const float* __restrict__ vw, const float* __restrict__ vb,
                              const float* __restrict__ l2w, const float* __restrict__ l2b,
                              float* __restrict__ kbuf, float* __restrict__ vbuf) {
    __shared__ float sh[64];
    int g = blockIdx.x;
    int bl = g % (BATCH * LTXT);
    int blk = g / (BATCH * LTXT);
    int o = threadIdx.x;
    sh[o] = tf[bl * 64 + o];
    __syncthreads();
    const float* kr = kw + blk * 4096 + o * 64;
    const float* vr = vw + blk * 4096 + o * 64;
    float ka = kb[blk * 64 + o], va = vb[blk * 64 + o];
    for (int c2 = 0; c2 < 64; c2++) {
        float t = sh[c2];
        ka += t * kr[c2];
        va += t * vr[c2];
    }
    float s = ka;
    for (int off = 32; off; off >>= 1) s += __shfl_xor(s, off, 64);
    float mean = s * (1.0f / 64.0f);
    float d = ka - mean;
    float s2 = d * d;
    for (int off = 32; off; off >>= 1) s2 += __shfl_xor(s2, off, 64);
    float rstd = rsqrtf(s2 * (1.0f / 64.0f) + 1e-5f);
    size_t outi = (size_t)blk * (BATCH * LTXT * 64) + (size_t)bl * 64 + o;
    kbuf[outi] = d * rstd * l2w[blk * 64 + o] + l2b[blk * 64 + o];
    vbuf[outi] = va;
}

// ---------------- fused attention block: 512 threads = 64 pixels x 8 heads
// wave = one head over 64 consecutive pixels -> K/V addresses wave-uniform (scalar loads)
__global__ void __launch_bounds__(512)
attn_kernel(float* __restrict__ feat,
            const float* __restrict__ kbuf, const float* __restrict__ vbuf,
            const float* __restrict__ qw, const float* __restrict__ qb,
            const float* __restrict__ ow, const float* __restrict__ ob,
            const float* __restrict__ l1w, const float* __restrict__ l1b) {
    __shared__ float so[64][64];        // out-exchange [c][p]
    __shared__ float red[2][8][64];     // LN partial sums [sum/sumsq][h][p]

    int b = blockIdx.x >> 6;
    int tile = blockIdx.x & 63;
    int n0 = tile << 6;
    int h = threadIdx.x >> 6;   // head (wave-uniform)
    int p = threadIdx.x & 63;   // pixel within tile (lane)
    int n = n0 + p;
    float* fbase = feat + ((size_t)b << 18) + n0;

    // feat column for my pixel -> registers (coalesced: lanes are consecutive p)
    float f[64];
#pragma unroll
    for (int c = 0; c < 64; c++) f[c] = fbase[c * HW0 + p];

    // q projection for my head's 8 channels + positional encoding
    float px = (float)(n & 63) * (1.0f / 63.0f);
    float py = (float)(n >> 6) * (1.0f / 63.0f);
    float q[8];
    float s = 0.f, s2 = 0.f;
#pragma unroll
    for (int j = 0; j < 8; j++) {
        int o = h * 8 + j;
        const float4* wr = (const float4*)(qw + o * 64);   // wave-uniform -> scalar loads
        float acc = qb[o];
#pragma unroll
        for (int i = 0; i < 16; i++) {
            float4 w4 = wr[i];
            acc += w4.x * f[4*i] + w4.y * f[4*i+1] + w4.z * f[4*i+2] + w4.w * f[4*i+3];
        }
        acc += 0.05f * (o < 32 ? px : py);
        q[j] = acc;
        s += acc;
        s2 += acc * acc;
    }
    red[0][h][p] = s;
    red[1][h][p] = s2;
    __syncthreads();

    float ts = 0.f, ts2 = 0.f;
#pragma unroll
    for (int hh = 0; hh < 8; hh++) { ts += red[0][hh][p]; ts2 += red[1][hh][p]; }
    float mean = ts * (1.0f / 64.0f);
    float var = ts2 * (1.0f / 64.0f) - mean * mean;
    float rstd = rsqrtf(var + 1e-5f);
#pragma unroll
    for (int j = 0; j < 8; j++) {
        int o = h * 8 + j;
        q[j] = (q[j] - mean) * rstd * l1w[o] + l1b[o];
    }

    // cross attention, online softmax (K/V rows wave-uniform -> scalar loads)
    const float* kb_b = kbuf + (size_t)b * LTXT * 64 + h * 8;
    const float* vb_b = vbuf + (size_t)b * LTXT * 64 + h * 8;
    const float scale = 0.35355339059327373f;
    float m = -1e30f, ssum = 0.f;
    float acc[8] = {0.f,0.f,0.f,0.f,0.f,0.f,0.f,0.f};
    for (int l = 0; l < LTXT; l++) {
        const float4* kr = (const float4*)(kb_b + l * 64);
        float4 k0 = kr[0], k1 = kr[1];
        float sd = q[0]*k0.x + q[1]*k0.y + q[2]*k0.z + q[3]*k0.w
                 + q[4]*k1.x + q[5]*k1.y + q[6]*k1.z + q[7]*k1.w;
        sd *= scale;
        float mn = fmaxf(m, sd);
        float cf = __expf(m - mn);
        float e = __expf(sd - mn);
        ssum = ssum * cf + e;
        const float4* vr = (const float4*)(vb_b + l * 64);
        float4 v0 = vr[0], v1 = vr[1];
        acc[0] = acc[0]*cf + e*v0.x; acc[1] = acc[1]*cf + e*v0.y;
        acc[2] = acc[2]*cf + e*v0.z; acc[3] = acc[3]*cf + e*v0.w;
        acc[4] = acc[4]*cf + e*v1.x; acc[5] = acc[5]*cf + e*v1.y;
        acc[6] = acc[6]*cf + e*v1.z; acc[7] = acc[7]*cf + e*v1.w;
        m = mn;
    }
    float inv = 1.0f / ssum;
#pragma unroll
    for (int j = 0; j < 8; j++) so[h * 8 + j][p] = acc[j] * inv;
    __syncthreads();

    // out projection + residual; my head's 8 output channels for my pixel
#pragma unroll
    for (int j = 0; j < 8; j++) {
        int o = h * 8 + j;
        const float* wr = ow + o * 64;   // wave-uniform -> scalar loads
        float a = ob[o];
#pragma unroll
        for (int i = 0; i < 64; i++) a += wr[i] * so[i][p];
        fbase[o * HW0 + p] = a + f[o];
    }
}

// ---------------- upsample conv 3x3 (64 -> 256) + pixel shuffle r=2 + relu
// thread: 2x2 spatial x 8 co; blockIdx.y = co-group; weights staged to LDS [ci][kp][8]
__global__ void __launch_bounds__(256)
up_conv_kernel(const float* __restrict__ in, const float* __restrict__ w,
               const float* __restrict__ bias, float* __restrict__ out,
               int Hin, int Win) {
    __shared__ float sw[64 * 9 * 8];   // 18 KB
    int co0 = blockIdx.y * 8;
    for (int e = threadIdx.x; e < 4608; e += 256) {
        int j = e & 7;
        int kp = (e >> 3) % 9;
        int ci = e / 72;
        sw[e] = w[(co0 + j) * 576 + ci * 9 + kp];
    }
    __syncthreads();

    int Ht = Hin >> 1, Wt = Win >> 1;
    int t = blockIdx.x * 256 + threadIdx.x;
    if (t >= BATCH * Ht * Wt) return;
    int tw = t % Wt;
    int th = (t / Wt) % Ht;
    int b = t / (Wt * Ht);
    int h0 = th * 2, w0 = tw * 2;

    float acc[8][4];
#pragma unroll
    for (int j = 0; j < 8; j++) {
        float bv = bias[co0 + j];
#pragma unroll
        for (int u = 0; u < 4; u++) acc[j][u] = bv;
    }

    for (int ci = 0; ci < 64; ci++) {
        const float* base = in + (((size_t)b * 64 + ci) * Hin) * Win;
        float pin[4][4];
#pragma unroll
        for (int r = 0; r < 4; r++) {
            int y = h0 - 1 + r;
            bool yv = (unsigned)y < (unsigned)Hin;
            const float* xr = base + y * Win;
#pragma unroll
            for (int cc = 0; cc < 4; cc++) {
                int x = w0 - 1 + cc;
                pin[r][cc] = (yv && (unsigned)x < (unsigned)Win) ? xr[x] : 0.f;
            }
        }
        const float4* swp = (const float4*)(sw + ci * 72);
#pragma unroll
        for (int kp = 0; kp < 9; kp++) {
            float4 wa = swp[kp * 2];
            float4 wb = swp[kp * 2 + 1];
            int ky = kp / 3, kx = kp % 3;
            float w8[8] = {wa.x, wa.y, wa.z, wa.w, wb.x, wb.y, wb.z, wb.w};
#pragma unroll
            for (int j = 0; j < 8; j++) {
#pragma unroll
                for (int dy = 0; dy < 2; dy++) {
#pragma unroll
                    for (int dx = 0; dx < 2; dx++) {
                        acc[j][dy * 2 + dx] += pin[ky + dy][kx + dx] * w8[j];
                    }
                }
            }
        }
    }

    int Ho = Hin * 2, Wo = Win * 2;
#pragma unroll
    for (int j = 0; j < 8; j++) {
        int co = co0 + j;
        int c = co >> 2, r1 = (co >> 1) & 1, r2 = co & 1;
#pragma unroll
        for (int dy = 0; dy < 2; dy++) {
#pragma unroll
            for (int dx = 0; dx < 2; dx++) {
                float v = fmaxf(acc[j][dy * 2 + dx], 0.f);
                out[(((size_t)b * 64 + c) * Ho + (2 * (h0 + dy) + r1)) * Wo + (2 * (w0 + dx) + r2)] = v;
            }
        }
    }
}

// ---------------- final 3x3 conv: [8,64,256,256] -> [8,3,256,256]; thread: 2x2 px, 3 co
__global__ void __launch_bounds__(256)
final_conv_kernel(const float* __restrict__ in, const float* __restrict__ w,
                  const float* __restrict__ bias, float* __restrict__ out) {
    __shared__ float sw[64 * 9 * 3];   // 6.75 KB
    for (int e = threadIdx.x; e < 1728; e += 256) {
        int j = e % 3;
        int kp = (e / 3) % 9;
        int ci = e / 27;
        sw[e] = w[j * 576 + ci * 9 + kp];
    }
    __syncthreads();

    int t = blockIdx.x * 256 + threadIdx.x;
    if (t >= BATCH * 128 * 128) return;
    int tw = t % 128;
    int th = (t / 128) % 128;
    int b = t / (128 * 128);
    int h0 = th * 2, w0 = tw * 2;

    float acc[3][4];
#pragma unroll
    for (int j = 0; j < 3; j++) {
        float bv = bias[j];
#pragma unroll
        for (int u = 0; u < 4; u++) acc[j][u] = bv;
    }

    for (int ci = 0; ci < 64; ci++) {
        const float* base = in + (((size_t)b * 64 + ci) * 256) * 256;
        float pin[4][4];
#pragma unroll
        for (int r = 0; r < 4; r++) {
            int y = h0 - 1 + r;
            bool yv = (unsigned)y < 256u;
            const float* xr = base + y * 256;
#pragma unroll
            for (int cc = 0; cc < 4; cc++) {
                int x = w0 - 1 + cc;
                pin[r][cc] = (yv && (unsigned)x < 256u) ? xr[x] : 0.f;
            }
        }
        const float* swp = sw + ci * 27;
#pragma unroll
        for (int kp = 0; kp < 9; kp++) {
            int ky = kp / 3, kx = kp % 3;
#pragma unroll
            for (int j = 0; j < 3; j++) {
                float wv = swp[kp * 3 + j];
#pragma unroll
                for (int dy = 0; dy < 2; dy++) {
#pragma unroll
                    for (int dx = 0; dx < 2; dx++) {
                        acc[j][dy * 2 + dx] += pin[ky + dy][kx + dx] * wv;
                    }
                }
            }
        }
    }

#pragma unroll
    for (int j = 0; j < 3; j++) {
#pragma unroll
        for (int dy = 0; dy < 2; dy++) {
#pragma unroll
            for (int dx = 0; dx < 2; dx++) {
                out[(((size_t)b * 3 + j) * 256 + (h0 + dy)) * 256 + (w0 + dx)] = acc[j][dy * 2 + dx];
            }
        }
    }
}

extern "C" void kernel_launch(void* const* d_in, const int* in_sizes, int n_in,
                              void* d_out, int out_size, void* d_ws, size_t ws_size,
                              hipStream_t stream) {
    const float* x      = (const float*)d_in[0];
    const float* th     = (const float*)d_in[1];
    const float* proj_w = (const float*)d_in[2];
    const float* proj_b = (const float*)d_in[3];
    const float* cf_w   = (const float*)d_in[4];
    const float* cf_b   = (const float*)d_in[5];
    const float* qw     = (const float*)d_in[6];
    const float* qb     = (const float*)d_in[7];
    const float* kw     = (const float*)d_in[8];
    const float* kb     = (const float*)d_in[9];
    const float* vw     = (const float*)d_in[10];
    const float* vb     = (const float*)d_in[11];
    const float* ow     = (const float*)d_in[12];
    const float* ob     = (const float*)d_in[13];
    const float* l1w    = (const float*)d_in[14];
    const float* l1b    = (const float*)d_in[15];
    const float* l2w    = (const float*)d_in[16];
    const float* l2b    = (const float*)d_in[17];
    const float* up_w   = (const float*)d_in[18];
    const float* up_b   = (const float*)d_in[19];
    const float* cl_w   = (const float*)d_in[20];
    const float* cl_b   = (const float*)d_in[21];

    float* ws   = (float*)d_ws;
    float* feat = ws;                       // 2,097,152
    float* tf   = feat + 2097152;           // 39,424
    float* up1  = tf + 39424;               // 8,388,608
    float* up2  = up1 + 8388608;            // 33,554,432
    // kbuf/vbuf live inside the up2 region (consumed before up2 is written)
    float* kbuf = up2;                      // 16*39,424 = 630,784
    float* vbuf = kbuf + 630784;            // 630,784

    hipLaunchKernelGGL(text_proj_kernel, dim3(BATCH * LTXT), dim3(64), 0, stream,
                       th, proj_w, proj_b, tf);
    hipLaunchKernelGGL(kv_all_kernel, dim3(16 * BATCH * LTXT), dim3(64), 0, stream,
                       tf, kw, kb, vw, vb, l2w, l2b, kbuf, vbuf);
    hipLaunchKernelGGL(conv_in_kernel, dim3((BATCH * C * HW0) / 256), dim3(256), 0, stream,
                       x, cf_w, cf_b, feat);

    for (int i = 0; i < 16; i++) {
        hipLaunchKernelGGL(attn_kernel, dim3(BATCH * (HW0 / 64)), dim3(512), 0, stream,
                           feat, kbuf + (size_t)i * BATCH * LTXT * 64,
                           vbuf + (size_t)i * BATCH * LTXT * 64,
                           qw + i * 4096, qb + i * 64,
                           ow + i * 4096, ob + i * 64, l1w + i * 64, l1b + i * 64);
    }

    hipLaunchKernelGGL(up_conv_kernel, dim3((BATCH * 32 * 32 + 255) / 256, 32), dim3(256), 0, stream,
                       feat, up_w, up_b, up1, 64, 64);
    hipLaunchKernelGGL(up_conv_kernel, dim3((BATCH * 64 * 64 + 255) / 256, 32), dim3(256), 0, stream,
                       up1, up_w + 256 * 576, up_b + 256, up2, 128, 128);
    hipLaunchKernelGGL(final_conv_kernel, dim3((BATCH * 128 * 128 + 255) / 256), dim3(256), 0, stream,
                       up2, cl_w, cl_b, (float*)d_out);
}

// Round 3
// 2036.581 us; speedup vs baseline: 5.5584x; 1.2225x over previous
//
#include <hip/hip_runtime.h>
#include <math.h>

#define BATCH 8
#define C 64
#define NH 8
#define HD 8
#define LTXT 77
#define H0 64
#define W0 64
#define HW0 (H0*W0)

// ---------------- text projection: tf[b,l,c] = th[b,l,:] . proj_w[c,:] + proj_b[c]
__global__ void text_proj_kernel(const float* __restrict__ th, const float* __restrict__ pw,
                                 const float* __restrict__ pb, float* __restrict__ tf) {
    __shared__ float sh[512];
    int bl = blockIdx.x;
    int c = threadIdx.x;
    const float* row = th + (size_t)bl * 512;
    for (int i = c; i < 512; i += 64) sh[i] = row[i];
    __syncthreads();
    const float* wrow = pw + c * 512;
    float acc = pb[c];
    for (int i = 0; i < 512; i += 4) {
        acc += sh[i] * wrow[i] + sh[i+1] * wrow[i+1] + sh[i+2] * wrow[i+2] + sh[i+3] * wrow[i+3];
    }
    tf[bl * 64 + c] = acc;
}

// ---------------- first 3x3 conv: x[8,3,64,64] -> feat[8,64,64,64], SAME pad
__global__ void conv_in_kernel(const float* __restrict__ x, const float* __restrict__ w,
                               const float* __restrict__ bias, float* __restrict__ feat) {
    int idx = blockIdx.x * blockDim.x + threadIdx.x;
    if (idx >= BATCH * C * HW0) return;
    int wx = idx & 63;
    int h = (idx >> 6) & 63;
    int o = (idx >> 12) & 63;
    int b = idx >> 18;
    const float* wr = w + o * 27;
    float acc = bias[o];
    for (int ci = 0; ci < 3; ci++) {
        for (int ky = 0; ky < 3; ky++) {
            int y = h + ky - 1;
            if ((unsigned)y >= 64u) continue;
            const float* xr = x + (((size_t)b * 3 + ci) * 64 + y) * 64;
            const float* wk = wr + ci * 9 + ky * 3;
            if (wx > 0) acc += xr[wx - 1] * wk[0];
            acc += xr[wx] * wk[1];
            if (wx < 63) acc += xr[wx + 1] * wk[2];
        }
    }
    feat[idx] = acc;
}

// ---------------- K/V for ALL 16 blocks upfront
__global__ void kv_all_kernel(const float* __restrict__ tf,
                              const float* __restrict__ kw, const float* __restrict__ kb,
                              const float* __restrict__ vw, const float* __restrict__ vb,
                              const float* __restrict__ l2w, const float* __restrict__ l2b,
                              float* __restrict__ kbuf, float* __restrict__ vbuf) {
    __shared__ float sh[64];
    int g = blockIdx.x;
    int bl = g % (BATCH * LTXT);
    int blk = g / (BATCH * LTXT);
    int o = threadIdx.x;
    sh[o] = tf[bl * 64 + o];
    __syncthreads();
    const float* kr = kw + blk * 4096 + o * 64;
    const float* vr = vw + blk * 4096 + o * 64;
    float ka = kb[blk * 64 + o], va = vb[blk * 64 + o];
    for (int c2 = 0; c2 < 64; c2++) {
        float t = sh[c2];
        ka += t * kr[c2];
        va += t * vr[c2];
    }
    float s = ka;
    for (int off = 32; off; off >>= 1) s += __shfl_xor(s, off, 64);
    float mean = s * (1.0f / 64.0f);
    float d = ka - mean;
    float s2 = d * d;
    for (int off = 32; off; off >>= 1) s2 += __shfl_xor(s2, off, 64);
    float rstd = rsqrtf(s2 * (1.0f / 64.0f) + 1e-5f);
    size_t outi = (size_t)blk * (BATCH * LTXT * 64) + (size_t)bl * 64 + o;
    kbuf[outi] = d * rstd * l2w[blk * 64 + o] + l2b[blk * 64 + o];
    vbuf[outi] = va;
}

// ---------------- fused attention block: 512 threads = 64 pixels x 8 heads
// feat tile staged in LDS; per-channel LDS read feeds 8 FMAs w/ scalar weights
__global__ void __launch_bounds__(512, 4)
attn_kernel(float* __restrict__ feat,
            const float* __restrict__ kbuf, const float* __restrict__ vbuf,
            const float* __restrict__ qw, const float* __restrict__ qb,
            const float* __restrict__ ow, const float* __restrict__ ob,
            const float* __restrict__ l1w, const float* __restrict__ l1b) {
    __shared__ float sf[64][64];        // feat tile [c][p]
    __shared__ float so[64][64];        // attn-out exchange [c][p]
    __shared__ float red[2][8][64];     // LN partials

    int b = blockIdx.x >> 6;
    int tile = blockIdx.x & 63;
    int n0 = tile << 6;
    int h = __builtin_amdgcn_readfirstlane(threadIdx.x >> 6);  // head, wave-uniform
    int p = threadIdx.x & 63;
    int o0 = h * 8;
    float* fbase = feat + ((size_t)b << 18) + n0;

    // stage feat tile (coalesced along p)
    for (int c = h; c < 64; c += 8) sf[c][p] = fbase[c * HW0 + p];
    __syncthreads();

    // q projection for my head's 8 channels
    float q[8];
#pragma unroll
    for (int j = 0; j < 8; j++) q[j] = qb[o0 + j];
#pragma unroll 4
    for (int cc = 0; cc < 64; cc += 4) {
        float f0 = sf[cc][p], f1 = sf[cc+1][p], f2 = sf[cc+2][p], f3 = sf[cc+3][p];
#pragma unroll
        for (int j = 0; j < 8; j++) {
            const float* wr = qw + (o0 + j) * 64 + cc;   // wave-uniform -> s_load
            q[j] += f0 * wr[0] + f1 * wr[1] + f2 * wr[2] + f3 * wr[3];
        }
    }

    // positional encoding: tile == image row, so py is wave-uniform
    float px = (float)p * (1.0f / 63.0f);
    float py = (float)tile * (1.0f / 63.0f);
    float pev = 0.05f * ((h < 4) ? px : py);
    float s = 0.f, s2 = 0.f;
#pragma unroll
    for (int j = 0; j < 8; j++) {
        q[j] += pev;
        s += q[j];
        s2 += q[j] * q[j];
    }
    red[0][h][p] = s;
    red[1][h][p] = s2;
    __syncthreads();

    float ts = 0.f, ts2 = 0.f;
#pragma unroll
    for (int hh = 0; hh < 8; hh++) { ts += red[0][hh][p]; ts2 += red[1][hh][p]; }
    float mean = ts * (1.0f / 64.0f);
    float var = ts2 * (1.0f / 64.0f) - mean * mean;
    float rstd = rsqrtf(var + 1e-5f);
#pragma unroll
    for (int j = 0; j < 8; j++) q[j] = (q[j] - mean) * rstd * l1w[o0 + j] + l1b[o0 + j];

    // cross attention (K/V rows wave-uniform -> scalar loads), online softmax
    const float* kb_b = kbuf + (size_t)b * LTXT * 64 + o0;
    const float* vb_b = vbuf + (size_t)b * LTXT * 64 + o0;
    const float scale = 0.35355339059327373f;
    float m = -1e30f, ssum = 0.f;
    float acc[8] = {0.f,0.f,0.f,0.f,0.f,0.f,0.f,0.f};
    for (int l = 0; l < LTXT; l++) {
        const float4* kr = (const float4*)(kb_b + l * 64);
        float4 k0 = kr[0], k1 = kr[1];
        float sd = q[0]*k0.x + q[1]*k0.y + q[2]*k0.z + q[3]*k0.w
                 + q[4]*k1.x + q[5]*k1.y + q[6]*k1.z + q[7]*k1.w;
        sd *= scale;
        float mn = fmaxf(m, sd);
        float cf = __expf(m - mn);
        float e = __expf(sd - mn);
        ssum = ssum * cf + e;
        const float4* vr = (const float4*)(vb_b + l * 64);
        float4 v0 = vr[0], v1 = vr[1];
        acc[0] = acc[0]*cf + e*v0.x; acc[1] = acc[1]*cf + e*v0.y;
        acc[2] = acc[2]*cf + e*v0.z; acc[3] = acc[3]*cf + e*v0.w;
        acc[4] = acc[4]*cf + e*v1.x; acc[5] = acc[5]*cf + e*v1.y;
        acc[6] = acc[6]*cf + e*v1.z; acc[7] = acc[7]*cf + e*v1.w;
        m = mn;
    }
    float inv = 1.0f / ssum;
#pragma unroll
    for (int j = 0; j < 8; j++) so[o0 + j][p] = acc[j] * inv;
    __syncthreads();

    // out projection + residual
    float r[8];
#pragma unroll
    for (int j = 0; j < 8; j++) r[j] = ob[o0 + j];
#pragma unroll 4
    for (int cc = 0; cc < 64; cc += 4) {
        float s0 = so[cc][p], s1 = so[cc+1][p], s2v = so[cc+2][p], s3 = so[cc+3][p];
#pragma unroll
        for (int j = 0; j < 8; j++) {
            const float* wr = ow + (o0 + j) * 64 + cc;   // wave-uniform -> s_load
            r[j] += s0 * wr[0] + s1 * wr[1] + s2v * wr[2] + s3 * wr[3];
        }
    }
#pragma unroll
    for (int j = 0; j < 8; j++) {
        fbase[(o0 + j) * HW0 + p] = r[j] + sf[o0 + j][p];
    }
}

// ---------------- upsample conv (2x2 px x 8 co per thread) -- stage 1
__global__ void __launch_bounds__(256)
up_conv_kernel(const float* __restrict__ in, const float* __restrict__ w,
               const float* __restrict__ bias, float* __restrict__ out,
               int Hin, int Win) {
    __shared__ float sw[64 * 9 * 8];
    int co0 = blockIdx.y * 8;
    for (int e = threadIdx.x; e < 4608; e += 256) {
        int j = e & 7;
        int kp = (e >> 3) % 9;
        int ci = e / 72;
        sw[e] = w[(co0 + j) * 576 + ci * 9 + kp];
    }
    __syncthreads();

    int Ht = Hin >> 1, Wt = Win >> 1;
    int t = blockIdx.x * 256 + threadIdx.x;
    if (t >= BATCH * Ht * Wt) return;
    int tw = t % Wt;
    int th = (t / Wt) % Ht;
    int b = t / (Wt * Ht);
    int h0 = th * 2, w0 = tw * 2;

    float acc[8][4];
#pragma unroll
    for (int j = 0; j < 8; j++) {
        float bv = bias[co0 + j];
#pragma unroll
        for (int u = 0; u < 4; u++) acc[j][u] = bv;
    }

    for (int ci = 0; ci < 64; ci++) {
        const float* base = in + (((size_t)b * 64 + ci) * Hin) * Win;
        float pin[4][4];
#pragma unroll
        for (int r = 0; r < 4; r++) {
            int y = h0 - 1 + r;
            bool yv = (unsigned)y < (unsigned)Hin;
            const float* xr = base + y * Win;
#pragma unroll
            for (int cc = 0; cc < 4; cc++) {
                int x = w0 - 1 + cc;
                pin[r][cc] = (yv && (unsigned)x < (unsigned)Win) ? xr[x] : 0.f;
            }
        }
        const float4* swp = (const float4*)(sw + ci * 72);
#pragma unroll
        for (int kp = 0; kp < 9; kp++) {
            float4 wa = swp[kp * 2];
            float4 wb = swp[kp * 2 + 1];
            int ky = kp / 3, kx = kp % 3;
            float w8[8] = {wa.x, wa.y, wa.z, wa.w, wb.x, wb.y, wb.z, wb.w};
#pragma unroll
            for (int j = 0; j < 8; j++) {
#pragma unroll
                for (int dy = 0; dy < 2; dy++) {
#pragma unroll
                    for (int dx = 0; dx < 2; dx++) {
                        acc[j][dy * 2 + dx] += pin[ky + dy][kx + dx] * w8[j];
                    }
                }
            }
        }
    }

    int Ho = Hin * 2, Wo = Win * 2;
#pragma unroll
    for (int j = 0; j < 8; j++) {
        int co = co0 + j;
        int c = co >> 2, r1 = (co >> 1) & 1, r2 = co & 1;
#pragma unroll
        for (int dy = 0; dy < 2; dy++) {
#pragma unroll
            for (int dx = 0; dx < 2; dx++) {
                float v = fmaxf(acc[j][dy * 2 + dx], 0.f);
                out[(((size_t)b * 64 + c) * Ho + (2 * (h0 + dy) + r1)) * Wo + (2 * (w0 + dx) + r2)] = v;
            }
        }
    }
}

// ---------------- upsample conv (2x4 px x 8 co per thread) -- stage 2
__global__ void __launch_bounds__(256)
up_conv4_kernel(const float* __restrict__ in, const float* __restrict__ w,
                const float* __restrict__ bias, float* __restrict__ out,
                int Hin, int Win) {
    __shared__ float sw[64 * 9 * 8];
    int co0 = blockIdx.y * 8;
    for (int e = threadIdx.x; e < 4608; e += 256) {
        int j = e & 7;
        int kp = (e >> 3) % 9;
        int ci = e / 72;
        sw[e] = w[(co0 + j) * 576 + ci * 9 + kp];
    }
    __syncthreads();

    int Ht = Hin >> 1, Wt = Win >> 2;
    int t = blockIdx.x * 256 + threadIdx.x;
    if (t >= BATCH * Ht * Wt) return;
    int tw = t % Wt;
    int th = (t / Wt) % Ht;
    int b = t / (Wt * Ht);
    int h0 = th * 2, w0 = tw * 4;

    float acc[8][8];   // [co][dy*4+dx]
#pragma unroll
    for (int j = 0; j < 8; j++) {
        float bv = bias[co0 + j];
#pragma unroll
        for (int u = 0; u < 8; u++) acc[j][u] = bv;
    }

    for (int ci = 0; ci < 64; ci++) {
        const float* base = in + (((size_t)b * 64 + ci) * Hin) * Win;
        float pin[4][6];
#pragma unroll
        for (int r = 0; r < 4; r++) {
            int y = h0 - 1 + r;
            bool yv = (unsigned)y < (unsigned)Hin;
            const float* xr = base + y * Win;
#pragma unroll
            for (int cc = 0; cc < 6; cc++) {
                int x = w0 - 1 + cc;
                pin[r][cc] = (yv && (unsigned)x < (unsigned)Win) ? xr[x] : 0.f;
            }
        }
        const float4* swp = (const float4*)(sw + ci * 72);
#pragma unroll
        for (int kp = 0; kp < 9; kp++) {
            float4 wa = swp[kp * 2];
            float4 wb = swp[kp * 2 + 1];
            int ky = kp / 3, kx = kp % 3;
            float w8[8] = {wa.x, wa.y, wa.z, wa.w, wb.x, wb.y, wb.z, wb.w};
#pragma unroll
            for (int j = 0; j < 8; j++) {
#pragma unroll
                for (int dy = 0; dy < 2; dy++) {
#pragma unroll
                    for (int dx = 0; dx < 4; dx++) {
                        acc[j][dy * 4 + dx] += pin[ky + dy][kx + dx] * w8[j];
                    }
                }
            }
        }
    }

    int Ho = Hin * 2, Wo = Win * 2;
#pragma unroll
    for (int j = 0; j < 8; j++) {
        int co = co0 + j;
        int c = co >> 2, r1 = (co >> 1) & 1, r2 = co & 1;
#pragma unroll
        for (int dy = 0; dy < 2; dy++) {
#pragma unroll
            for (int dx = 0; dx < 4; dx++) {
                float v = fmaxf(acc[j][dy * 4 + dx], 0.f);
                out[(((size_t)b * 64 + c) * Ho + (2 * (h0 + dy) + r1)) * Wo + (2 * (w0 + dx) + r2)] = v;
            }
        }
    }
}

// ---------------- final 3x3 conv: [8,64,256,256] -> [8,3,256,256]; thread: 2x2 px, 3 co
__global__ void __launch_bounds__(256)
final_conv_kernel(const float* __restrict__ in, const float* __restrict__ w,
                  const float* __restrict__ bias, float* __restrict__ out) {
    __shared__ float sw[64 * 9 * 3];
    for (int e = threadIdx.x; e < 1728; e += 256) {
        int j = e % 3;
        int kp = (e / 3) % 9;
        int ci = e / 27;
        sw[e] = w[j * 576 + ci * 9 + kp];
    }
    __syncthreads();

    int t = blockIdx.x * 256 + threadIdx.x;
    if (t >= BATCH * 128 * 128) return;
    int tw = t % 128;
    int th = (t / 128) % 128;
    int b = t / (128 * 128);
    int h0 = th * 2, w0 = tw * 2;

    float acc[3][4];
#pragma unroll
    for (int j = 0; j < 3; j++) {
        float bv = bias[j];
#pragma unroll
        for (int u = 0; u < 4; u++) acc[j][u] = bv;
    }

    for (int ci = 0; ci < 64; ci++) {
        const float* base = in + (((size_t)b * 64 + ci) * 256) * 256;
        float pin[4][4];
#pragma unroll
        for (int r = 0; r < 4; r++) {
            int y = h0 - 1 + r;
            bool yv = (unsigned)y < 256u;
            const float* xr = base + y * 256;
#pragma unroll
            for (int cc = 0; cc < 4; cc++) {
                int x = w0 - 1 + cc;
                pin[r][cc] = (yv && (unsigned)x < 256u) ? xr[x] : 0.f;
            }
        }
        const float* swp = sw + ci * 27;
#pragma unroll
        for (int kp = 0; kp < 9; kp++) {
            int ky = kp / 3, kx = kp % 3;
#pragma unroll
            for (int j = 0; j < 3; j++) {
                float wv = swp[kp * 3 + j];
#pragma unroll
                for (int dy = 0; dy < 2; dy++) {
#pragma unroll
                    for (int dx = 0; dx < 2; dx++) {
                        acc[j][dy * 2 + dx] += pin[ky + dy][kx + dx] * wv;
                    }
                }
            }
        }
    }

#pragma unroll
    for (int j = 0; j < 3; j++) {
#pragma unroll
        for (int dy = 0; dy < 2; dy++) {
#pragma unroll
            for (int dx = 0; dx < 2; dx++) {
                out[(((size_t)b * 3 + j) * 256 + (h0 + dy)) * 256 + (w0 + dx)] = acc[j][dy * 2 + dx];
            }
        }
    }
}

extern "C" void kernel_launch(void* const* d_in, const int* in_sizes, int n_in,
                              void* d_out, int out_size, void* d_ws, size_t ws_size,
                              hipStream_t stream) {
    const float* x      = (const float*)d_in[0];
    const float* th     = (const float*)d_in[1];
    const float* proj_w = (const float*)d_in[2];
    const float* proj_b = (const float*)d_in[3];
    const float* cf_w   = (const float*)d_in[4];
    const float* cf_b   = (const float*)d_in[5];
    const float* qw     = (const float*)d_in[6];
    const float* qb     = (const float*)d_in[7];
    const float* kw     = (const float*)d_in[8];
    const float* kb     = (const float*)d_in[9];
    const float* vw     = (const float*)d_in[10];
    const float* vb     = (const float*)d_in[11];
    const float* ow     = (const float*)d_in[12];
    const float* ob     = (const float*)d_in[13];
    const float* l1w    = (const float*)d_in[14];
    const float* l1b    = (const float*)d_in[15];
    const float* l2w    = (const float*)d_in[16];
    const float* l2b    = (const float*)d_in[17];
    const float* up_w   = (const float*)d_in[18];
    const float* up_b   = (const float*)d_in[19];
    const float* cl_w   = (const float*)d_in[20];
    const float* cl_b   = (const float*)d_in[21];

    float* ws   = (float*)d_ws;
    float* feat = ws;                       // 2,097,152
    float* tf   = feat + 2097152;           // 39,424
    float* up1  = tf + 39424;               // 8,388,608
    float* up2  = up1 + 8388608;            // 33,554,432
    // kbuf/vbuf live inside the up2 region (consumed before up2 is written)
    float* kbuf = up2;                      // 16*39,424 = 630,784
    float* vbuf = kbuf + 630784;            // 630,784

    hipLaunchKernelGGL(text_proj_kernel, dim3(BATCH * LTXT), dim3(64), 0, stream,
                       th, proj_w, proj_b, tf);
    hipLaunchKernelGGL(kv_all_kernel, dim3(16 * BATCH * LTXT), dim3(64), 0, stream,
                       tf, kw, kb, vw, vb, l2w, l2b, kbuf, vbuf);
    hipLaunchKernelGGL(conv_in_kernel, dim3((BATCH * C * HW0) / 256), dim3(256), 0, stream,
                       x, cf_w, cf_b, feat);

    for (int i = 0; i < 16; i++) {
        hipLaunchKernelGGL(attn_kernel, dim3(BATCH * (HW0 / 64)), dim3(512), 0, stream,
                           feat, kbuf + (size_t)i * BATCH * LTXT * 64,
                           vbuf + (size_t)i * BATCH * LTXT * 64,
                           qw + i * 4096, qb + i * 64,
                           ow + i * 4096, ob + i * 64, l1w + i * 64, l1b + i * 64);
    }

    hipLaunchKernelGGL(up_conv_kernel, dim3((BATCH * 32 * 32 + 255) / 256, 32), dim3(256), 0, stream,
                       feat, up_w, up_b, up1, 64, 64);
    hipLaunchKernelGGL(up_conv4_kernel, dim3((BATCH * 64 * 32 + 255) / 256, 32), dim3(256), 0, stream,
                       up1, up_w + 256 * 576, up_b + 256, up2, 128, 128);
    hipLaunchKernelGGL(final_conv_kernel, dim3((BATCH * 128 * 128 + 255) / 256), dim3(256), 0, stream,
                       up2, cl_w, cl_b, (float*)d_out);
}

// Round 4
// 1135.652 us; speedup vs baseline: 9.9680x; 1.7933x over previous
//
#include <hip/hip_runtime.h>
#include <math.h>

#define BATCH 8
#define C 64
#define NH 8
#define HD 8
#define LTXT 77
#define H0 64
#define W0 64
#define HW0 (H0*W0)

typedef __attribute__((ext_vector_type(8))) short bfrag;    // 8 bf16 (4 VGPR)
typedef __attribute__((ext_vector_type(4))) float ffrag;    // 4 fp32 acc
typedef __attribute__((ext_vector_type(8))) unsigned short us8;

__device__ __forceinline__ unsigned short f2bf(float f) {
    unsigned u = __builtin_bit_cast(unsigned, f);
    u += 0x7fff + ((u >> 16) & 1);   // RNE
    return (unsigned short)(u >> 16);
}

// ---------------- text projection: tf[b,l,c] = th[b,l,:] . proj_w[c,:] + proj_b[c]
__global__ void text_proj_kernel(const float* __restrict__ th, const float* __restrict__ pw,
                                 const float* __restrict__ pb, float* __restrict__ tf) {
    __shared__ float sh[512];
    int bl = blockIdx.x;
    int c = threadIdx.x;
    const float* row = th + (size_t)bl * 512;
    for (int i = c; i < 512; i += 64) sh[i] = row[i];
    __syncthreads();
    const float* wrow = pw + c * 512;
    float acc = pb[c];
    for (int i = 0; i < 512; i += 4) {
        acc += sh[i] * wrow[i] + sh[i+1] * wrow[i+1] + sh[i+2] * wrow[i+2] + sh[i+3] * wrow[i+3];
    }
    tf[bl * 64 + c] = acc;
}

// ---------------- first 3x3 conv: x[8,3,64,64] -> feat[8,64,64,64] fp32 NCHW
__global__ void conv_in_kernel(const float* __restrict__ x, const float* __restrict__ w,
                               const float* __restrict__ bias, float* __restrict__ feat) {
    int idx = blockIdx.x * blockDim.x + threadIdx.x;
    if (idx >= BATCH * C * HW0) return;
    int wx = idx & 63;
    int h = (idx >> 6) & 63;
    int o = (idx >> 12) & 63;
    int b = idx >> 18;
    const float* wr = w + o * 27;
    float acc = bias[o];
    for (int ci = 0; ci < 3; ci++) {
        for (int ky = 0; ky < 3; ky++) {
            int y = h + ky - 1;
            if ((unsigned)y >= 64u) continue;
            const float* xr = x + (((size_t)b * 3 + ci) * 64 + y) * 64;
            const float* wk = wr + ci * 9 + ky * 3;
            if (wx > 0) acc += xr[wx - 1] * wk[0];
            acc += xr[wx] * wk[1];
            if (wx < 63) acc += xr[wx + 1] * wk[2];
        }
    }
    feat[idx] = acc;
}

// ---------------- K/V for ALL 16 blocks upfront
__global__ void kv_all_kernel(const float* __restrict__ tf,
                              const float* __restrict__ kw, const float* __restrict__ kb,
                              const float* __restrict__ vw, const float* __restrict__ vb,
                              const float* __restrict__ l2w, const float* __restrict__ l2b,
                              float* __restrict__ kbuf, float* __restrict__ vbuf) {
    __shared__ float sh[64];
    int g = blockIdx.x;
    int bl = g % (BATCH * LTXT);
    int blk = g / (BATCH * LTXT);
    int o = threadIdx.x;
    sh[o] = tf[bl * 64 + o];
    __syncthreads();
    const float* kr = kw + blk * 4096 + o * 64;
    const float* vr = vw + blk * 4096 + o * 64;
    float ka = kb[blk * 64 + o], va = vb[blk * 64 + o];
    for (int c2 = 0; c2 < 64; c2++) {
        float t = sh[c2];
        ka += t * kr[c2];
        va += t * vr[c2];
    }
    float s = ka;
    for (int off = 32; off; off >>= 1) s += __shfl_xor(s, off, 64);
    float mean = s * (1.0f / 64.0f);
    float d = ka - mean;
    float s2 = d * d;
    for (int off = 32; off; off >>= 1) s2 += __shfl_xor(s2, off, 64);
    float rstd = rsqrtf(s2 * (1.0f / 64.0f) + 1e-5f);
    size_t outi = (size_t)blk * (BATCH * LTXT * 64) + (size_t)bl * 64 + o;
    kbuf[outi] = d * rstd * l2w[blk * 64 + o] + l2b[blk * 64 + o];
    vbuf[outi] = va;
}

// ---------------- fused attention block: 512 threads = 64 pixels x 8 heads
__global__ void __launch_bounds__(512, 4)
attn_kernel(float* __restrict__ feat,
            const float* __restrict__ kbuf, const float* __restrict__ vbuf,
            const float* __restrict__ qw, const float* __restrict__ qb,
            const float* __restrict__ ow, const float* __restrict__ ob,
            const float* __restrict__ l1w, const float* __restrict__ l1b) {
    __shared__ float sf[64][64];
    __shared__ float so[64][64];
    __shared__ float red[2][8][64];

    int b = blockIdx.x >> 6;
    int tile = blockIdx.x & 63;
    int n0 = tile << 6;
    int h = __builtin_amdgcn_readfirstlane(threadIdx.x >> 6);
    int p = threadIdx.x & 63;
    int o0 = h * 8;
    float* fbase = feat + ((size_t)b << 18) + n0;

    for (int c = h; c < 64; c += 8) sf[c][p] = fbase[c * HW0 + p];
    __syncthreads();

    float q[8];
#pragma unroll
    for (int j = 0; j < 8; j++) q[j] = qb[o0 + j];
#pragma unroll 4
    for (int cc = 0; cc < 64; cc += 4) {
        float f0 = sf[cc][p], f1 = sf[cc+1][p], f2 = sf[cc+2][p], f3 = sf[cc+3][p];
#pragma unroll
        for (int j = 0; j < 8; j++) {
            const float* wr = qw + (o0 + j) * 64 + cc;
            q[j] += f0 * wr[0] + f1 * wr[1] + f2 * wr[2] + f3 * wr[3];
        }
    }

    float px = (float)p * (1.0f / 63.0f);
    float py = (float)tile * (1.0f / 63.0f);
    float pev = 0.05f * ((h < 4) ? px : py);
    float s = 0.f, s2 = 0.f;
#pragma unroll
    for (int j = 0; j < 8; j++) {
        q[j] += pev;
        s += q[j];
        s2 += q[j] * q[j];
    }
    red[0][h][p] = s;
    red[1][h][p] = s2;
    __syncthreads();

    float ts = 0.f, ts2 = 0.f;
#pragma unroll
    for (int hh = 0; hh < 8; hh++) { ts += red[0][hh][p]; ts2 += red[1][hh][p]; }
    float mean = ts * (1.0f / 64.0f);
    float var = ts2 * (1.0f / 64.0f) - mean * mean;
    float rstd = rsqrtf(var + 1e-5f);
#pragma unroll
    for (int j = 0; j < 8; j++) q[j] = (q[j] - mean) * rstd * l1w[o0 + j] + l1b[o0 + j];

    // cross attention — no max subtraction (scores bounded; math-identical)
    const float* kb_b = kbuf + (size_t)b * LTXT * 64 + o0;
    const float* vb_b = vbuf + (size_t)b * LTXT * 64 + o0;
    const float scale = 0.35355339059327373f;
    float ssum = 0.f;
    float acc[8] = {0.f,0.f,0.f,0.f,0.f,0.f,0.f,0.f};
    for (int l = 0; l < LTXT; l++) {
        const float4* kr = (const float4*)(kb_b + l * 64);
        float4 k0 = kr[0], k1 = kr[1];
        float sd = q[0]*k0.x + q[1]*k0.y + q[2]*k0.z + q[3]*k0.w
                 + q[4]*k1.x + q[5]*k1.y + q[6]*k1.z + q[7]*k1.w;
        float e = __expf(sd * scale);
        ssum += e;
        const float4* vr = (const float4*)(vb_b + l * 64);
        float4 v0 = vr[0], v1 = vr[1];
        acc[0] += e*v0.x; acc[1] += e*v0.y; acc[2] += e*v0.z; acc[3] += e*v0.w;
        acc[4] += e*v1.x; acc[5] += e*v1.y; acc[6] += e*v1.z; acc[7] += e*v1.w;
    }
    float inv = 1.0f / ssum;
#pragma unroll
    for (int j = 0; j < 8; j++) so[o0 + j][p] = acc[j] * inv;
    __syncthreads();

    float r[8];
#pragma unroll
    for (int j = 0; j < 8; j++) r[j] = ob[o0 + j];
#pragma unroll 4
    for (int cc = 0; cc < 64; cc += 4) {
        float s0 = so[cc][p], s1 = so[cc+1][p], s2v = so[cc+2][p], s3 = so[cc+3][p];
#pragma unroll
        for (int j = 0; j < 8; j++) {
            const float* wr = ow + (o0 + j) * 64 + cc;
            r[j] += s0 * wr[0] + s1 * wr[1] + s2v * wr[2] + s3 * wr[3];
        }
    }
#pragma unroll
    for (int j = 0; j < 8; j++) {
        fbase[(o0 + j) * HW0 + p] = r[j] + sf[o0 + j][p];
    }
}

// ---------------- NCHW fp32 -> NHWC bf16 transpose (feat -> X1)
__global__ void __launch_bounds__(256)
nchw2nhwc_kernel(const float* __restrict__ feat, unsigned short* __restrict__ X1) {
    __shared__ float tile[64][65];
    int blk = blockIdx.x;
    int b = blk >> 6;
    int p0 = (blk & 63) << 6;
    int wv = threadIdx.x >> 6, lane = threadIdx.x & 63;
#pragma unroll
    for (int i = 0; i < 16; i++) {
        int c = wv * 16 + i;
        tile[c][lane] = feat[((size_t)b * 64 + c) * 4096 + p0 + lane];
    }
    __syncthreads();
    int p = threadIdx.x >> 2, cg = threadIdx.x & 3;
    us8 v0, v1;
#pragma unroll
    for (int k = 0; k < 8; k++) v0[k] = f2bf(tile[cg * 16 + k][p]);
#pragma unroll
    for (int k = 0; k < 8; k++) v1[k] = f2bf(tile[cg * 16 + 8 + k][p]);
    unsigned short* dst = X1 + ((size_t)(b * 4096 + p0 + p)) * 64 + cg * 16;
    *(us8*)dst = v0;
    *(us8*)(dst + 8) = v1;
}

// ---------------- weight pack: up_w[st] [256co][64ci][9kp] fp32
// -> [9t][2s][4q][256 n'][8j] bf16, n' = c + 64*(2r1+r2), co = 4c+g
__global__ void pack_up_kernel(const float* __restrict__ up_w,
                               unsigned short* __restrict__ PW1,
                               unsigned short* __restrict__ PW2) {
    int e = blockIdx.x * 256 + threadIdx.x;   // < 147456
    const float* w = up_w + (size_t)blockIdx.y * 147456;
    unsigned short* d = blockIdx.y ? PW2 : PW1;
    int j = e & 7, n = (e >> 3) & 255, q = (e >> 11) & 3, s = (e >> 13) & 1, t = e >> 14;
    int c = n & 63, g = n >> 6;
    int co = 4 * c + g, ci = 32 * s + 8 * q + j;
    d[e] = f2bf(w[co * 576 + ci * 9 + t]);
}

// ---------------- weight pack final: cl_w [3][64][9] -> [9][2][4][16][8] (n>=3 zero)
__global__ void pack_final_kernel(const float* __restrict__ cl_w,
                                  unsigned short* __restrict__ PWF) {
    int e = blockIdx.x * 256 + threadIdx.x;   // < 9216
    int j = e & 7, n = (e >> 3) & 15, q = (e >> 7) & 3, s = (e >> 9) & 1, t = e >> 10;
    int ci = 32 * s + 8 * q + j;
    float v = (n < 3) ? cl_w[n * 576 + ci * 9 + t] : 0.f;
    PWF[e] = f2bf(v);
}

// ---------------- upsample conv as 9-tap implicit GEMM, MFMA 16x16x32 bf16
// block: 64 px (one row seg) x 256 co; wave = residue group g -> contiguous NHWC store
__global__ void __launch_bounds__(256)
upconv_mfma_kernel(const unsigned short* __restrict__ X, const unsigned short* __restrict__ Bp,
                   const float* __restrict__ bias, unsigned short* __restrict__ Y,
                   int Hin, int Win) {
    int wv = threadIdx.x >> 6;
    int lane = threadIdx.x & 63;
    int q = lane >> 4, n16 = lane & 15;
    int m0 = blockIdx.x * 64;
    int hw = Hin * Win;
    int b = m0 / hw, rem = m0 % hw;
    int h = rem / Win, w0 = rem % Win;
    const unsigned short* Xb = X + (size_t)b * hw * 64;

    ffrag acc[4][4];
#pragma unroll
    for (int i = 0; i < 4; i++)
#pragma unroll
        for (int j2 = 0; j2 < 4; j2++) acc[i][j2] = (ffrag)0.f;
    const bfrag zf = (bfrag)(short)0;

    for (int t = 0; t < 9; t++) {
        int dy = t / 3 - 1, dx = t % 3 - 1;
        int hh = h + dy;
        if ((unsigned)hh >= (unsigned)Hin) continue;
        bfrag af[4][2];
#pragma unroll
        for (int mt = 0; mt < 4; mt++) {
            int wp = w0 + mt * 16 + n16 + dx;
            bool ok = (unsigned)wp < (unsigned)Win;
            const unsigned short* src = Xb + ((size_t)hh * Win + wp) * 64 + q * 8;
            af[mt][0] = ok ? *(const bfrag*)src : zf;
            af[mt][1] = ok ? *(const bfrag*)(src + 32) : zf;
        }
#pragma unroll
        for (int s = 0; s < 2; s++) {
#pragma unroll
            for (int nt = 0; nt < 4; nt++) {
                bfrag bf = *(const bfrag*)(Bp + (size_t)((((t * 2 + s) * 4 + q) * 256) + wv * 64 + nt * 16 + n16) * 8);
#pragma unroll
                for (int mt = 0; mt < 4; mt++)
                    acc[mt][nt] = __builtin_amdgcn_mfma_f32_16x16x32_bf16(af[mt][s], bf, acc[mt][nt], 0, 0, 0);
            }
        }
    }

    float bv[4];
#pragma unroll
    for (int nt = 0; nt < 4; nt++) bv[nt] = bias[4 * (nt * 16 + n16) + wv];
    int r1 = wv >> 1, r2 = wv & 1;
    int Wo = Win * 2;
    unsigned short* Yb = Y + ((size_t)b * Hin * 2 * Wo + (size_t)(2 * h + r1) * Wo + r2) * 64;
#pragma unroll
    for (int mt = 0; mt < 4; mt++) {
#pragma unroll
        for (int r = 0; r < 4; r++) {
            int m = mt * 16 + q * 4 + r;   // C/D: row = quad*4 + reg
            unsigned short* dst = Yb + (size_t)(2 * (w0 + m)) * 64;
#pragma unroll
            for (int nt = 0; nt < 4; nt++) {
                float v = acc[mt][nt][r] + bv[nt];
                v = fmaxf(v, 0.f);
                dst[nt * 16 + n16] = f2bf(v);
            }
        }
    }
}

// ---------------- final conv as 9-tap implicit GEMM, N=16 (3 real), fp32 NCHW out
__global__ void __launch_bounds__(256)
final_mfma_kernel(const unsigned short* __restrict__ X, const unsigned short* __restrict__ Bp,
                  const float* __restrict__ bias, float* __restrict__ out) {
    int wv = threadIdx.x >> 6, lane = threadIdx.x & 63;
    int q = lane >> 4, n16 = lane & 15;
    int m0 = blockIdx.x * 256 + wv * 64;
    int b = m0 >> 16;
    int rem = m0 & 65535;
    int h = rem >> 8, w0 = rem & 255;
    const unsigned short* Xb = X + (size_t)b * 65536 * 64;

    ffrag acc[4];
#pragma unroll
    for (int i = 0; i < 4; i++) acc[i] = (ffrag)0.f;
    const bfrag zf = (bfrag)(short)0;

    for (int t = 0; t < 9; t++) {
        int dy = t / 3 - 1, dx = t % 3 - 1;
        int hh = h + dy;
        if ((unsigned)hh >= 256u) continue;
        bfrag af[4][2];
#pragma unroll
        for (int mt = 0; mt < 4; mt++) {
            int wp = w0 + mt * 16 + n16 + dx;
            bool ok = (unsigned)wp < 256u;
            const unsigned short* src = Xb + ((size_t)hh * 256 + wp) * 64 + q * 8;
            af[mt][0] = ok ? *(const bfrag*)src : zf;
            af[mt][1] = ok ? *(const bfrag*)(src + 32) : zf;
        }
#pragma unroll
        for (int s = 0; s < 2; s++) {
            bfrag bf = *(const bfrag*)(Bp + (size_t)((((t * 2 + s) * 4 + q) * 16) + n16) * 8);
#pragma unroll
            for (int mt = 0; mt < 4; mt++)
                acc[mt] = __builtin_amdgcn_mfma_f32_16x16x32_bf16(af[mt][s], bf, acc[mt], 0, 0, 0);
        }
    }

    if (n16 < 3) {
        float bj = bias[n16];
        float* ob = out + (((size_t)b * 3 + n16) * 256 + h) * 256;
#pragma unroll
        for (int mt = 0; mt < 4; mt++)
#pragma unroll
            for (int r = 0; r < 4; r++)
                ob[w0 + mt * 16 + q * 4 + r] = acc[mt][r] + bj;
    }
}

extern "C" void kernel_launch(void* const* d_in, const int* in_sizes, int n_in,
                              void* d_out, int out_size, void* d_ws, size_t ws_size,
                              hipStream_t stream) {
    const float* x      = (const float*)d_in[0];
    const float* th     = (const float*)d_in[1];
    const float* proj_w = (const float*)d_in[2];
    const float* proj_b = (const float*)d_in[3];
    const float* cf_w   = (const float*)d_in[4];
    const float* cf_b   = (const float*)d_in[5];
    const float* qw     = (const float*)d_in[6];
    const float* qb     = (const float*)d_in[7];
    const float* kw     = (const float*)d_in[8];
    const float* kb     = (const float*)d_in[9];
    const float* vw     = (const float*)d_in[10];
    const float* vb     = (const float*)d_in[11];
    const float* ow     = (const float*)d_in[12];
    const float* ob     = (const float*)d_in[13];
    const float* l1w    = (const float*)d_in[14];
    const float* l1b    = (const float*)d_in[15];
    const float* l2w    = (const float*)d_in[16];
    const float* l2b    = (const float*)d_in[17];
    const float* up_w   = (const float*)d_in[18];
    const float* up_b   = (const float*)d_in[19];
    const float* cl_w   = (const float*)d_in[20];
    const float* cl_b   = (const float*)d_in[21];

    float* ws   = (float*)d_ws;
    float* feat = ws;                         // 2,097,152 f
    float* tf   = feat + 2097152;             // 39,424 f
    float* kbuf = tf + 39424;                 // 630,784 f
    float* vbuf = kbuf + 630784;              // 630,784 f
    unsigned short* X1  = (unsigned short*)(vbuf + 630784);  // 2,097,152 us
    unsigned short* X2  = X1 + 2097152;       // 8,388,608 us
    unsigned short* X3  = X2 + 8388608;       // 33,554,432 us
    unsigned short* PW1 = X3 + 33554432;      // 147,456 us
    unsigned short* PW2 = PW1 + 147456;       // 147,456 us
    unsigned short* PWF = PW2 + 147456;       // 9,216 us

    hipLaunchKernelGGL(pack_up_kernel, dim3(576, 2), dim3(256), 0, stream, up_w, PW1, PW2);
    hipLaunchKernelGGL(pack_final_kernel, dim3(36), dim3(256), 0, stream, cl_w, PWF);
    hipLaunchKernelGGL(text_proj_kernel, dim3(BATCH * LTXT), dim3(64), 0, stream,
                       th, proj_w, proj_b, tf);
    hipLaunchKernelGGL(kv_all_kernel, dim3(16 * BATCH * LTXT), dim3(64), 0, stream,
                       tf, kw, kb, vw, vb, l2w, l2b, kbuf, vbuf);
    hipLaunchKernelGGL(conv_in_kernel, dim3((BATCH * C * HW0) / 256), dim3(256), 0, stream,
                       x, cf_w, cf_b, feat);

    for (int i = 0; i < 16; i++) {
        hipLaunchKernelGGL(attn_kernel, dim3(BATCH * (HW0 / 64)), dim3(512), 0, stream,
                           feat, kbuf + (size_t)i * BATCH * LTXT * 64,
                           vbuf + (size_t)i * BATCH * LTXT * 64,
                           qw + i * 4096, qb + i * 64,
                           ow + i * 4096, ob + i * 64, l1w + i * 64, l1b + i * 64);
    }

    hipLaunchKernelGGL(nchw2nhwc_kernel, dim3(512), dim3(256), 0, stream, feat, X1);
    hipLaunchKernelGGL(upconv_mfma_kernel, dim3(BATCH * 64 * 64 / 64), dim3(256), 0, stream,
                       X1, PW1, up_b, X2, 64, 64);
    hipLaunchKernelGGL(upconv_mfma_kernel, dim3(BATCH * 128 * 128 / 64), dim3(256), 0, stream,
                       X2, PW2, up_b + 256, X3, 128, 128);
    hipLaunchKernelGGL(final_mfma_kernel, dim3(BATCH * 256 * 256 / 256), dim3(256), 0, stream,
                       X3, PWF, cl_b, (float*)d_out);
}

// Round 5
// 1061.448 us; speedup vs baseline: 10.6648x; 1.0699x over previous
//
#include <hip/hip_runtime.h>
#include <math.h>

#define BATCH 8
#define C 64
#define NH 8
#define HD 8
#define LTXT 77
#define H0 64
#define W0 64
#define HW0 (H0*W0)

typedef __attribute__((ext_vector_type(8))) short bfrag;    // 8 bf16 (4 VGPR)
typedef __attribute__((ext_vector_type(4))) float ffrag;    // 4 fp32 acc
typedef __attribute__((ext_vector_type(8))) unsigned short us8;

__device__ __forceinline__ unsigned short f2bf(float f) {
    unsigned u = __builtin_bit_cast(unsigned, f);
    u += 0x7fff + ((u >> 16) & 1);   // RNE
    return (unsigned short)(u >> 16);
}

// ---------------- text projection: tf[b,l,c] = th[b,l,:] . proj_w[c,:] + proj_b[c]
__global__ void text_proj_kernel(const float* __restrict__ th, const float* __restrict__ pw,
                                 const float* __restrict__ pb, float* __restrict__ tf) {
    __shared__ float sh[512];
    int bl = blockIdx.x;
    int c = threadIdx.x;
    const float* row = th + (size_t)bl * 512;
    for (int i = c; i < 512; i += 64) sh[i] = row[i];
    __syncthreads();
    const float* wrow = pw + c * 512;
    float acc = pb[c];
    for (int i = 0; i < 512; i += 4) {
        acc += sh[i] * wrow[i] + sh[i+1] * wrow[i+1] + sh[i+2] * wrow[i+2] + sh[i+3] * wrow[i+3];
    }
    tf[bl * 64 + c] = acc;
}

// ---------------- first 3x3 conv: x[8,3,64,64] -> feat[8,64,64,64] fp32 NCHW
__global__ void conv_in_kernel(const float* __restrict__ x, const float* __restrict__ w,
                               const float* __restrict__ bias, float* __restrict__ feat) {
    int idx = blockIdx.x * blockDim.x + threadIdx.x;
    if (idx >= BATCH * C * HW0) return;
    int wx = idx & 63;
    int h = (idx >> 6) & 63;
    int o = (idx >> 12) & 63;
    int b = idx >> 18;
    const float* wr = w + o * 27;
    float acc = bias[o];
    for (int ci = 0; ci < 3; ci++) {
        for (int ky = 0; ky < 3; ky++) {
            int y = h + ky - 1;
            if ((unsigned)y >= 64u) continue;
            const float* xr = x + (((size_t)b * 3 + ci) * 64 + y) * 64;
            const float* wk = wr + ci * 9 + ky * 3;
            if (wx > 0) acc += xr[wx - 1] * wk[0];
            acc += xr[wx] * wk[1];
            if (wx < 63) acc += xr[wx + 1] * wk[2];
        }
    }
    feat[idx] = acc;
}

// ---------------- K/V for ALL 16 blocks upfront
__global__ void kv_all_kernel(const float* __restrict__ tf,
                              const float* __restrict__ kw, const float* __restrict__ kb,
                              const float* __restrict__ vw, const float* __restrict__ vb,
                              const float* __restrict__ l2w, const float* __restrict__ l2b,
                              float* __restrict__ kbuf, float* __restrict__ vbuf) {
    __shared__ float sh[64];
    int g = blockIdx.x;
    int bl = g % (BATCH * LTXT);
    int blk = g / (BATCH * LTXT);
    int o = threadIdx.x;
    sh[o] = tf[bl * 64 + o];
    __syncthreads();
    const float* kr = kw + blk * 4096 + o * 64;
    const float* vr = vw + blk * 4096 + o * 64;
    float ka = kb[blk * 64 + o], va = vb[blk * 64 + o];
    for (int c2 = 0; c2 < 64; c2++) {
        float t = sh[c2];
        ka += t * kr[c2];
        va += t * vr[c2];
    }
    float s = ka;
    for (int off = 32; off; off >>= 1) s += __shfl_xor(s, off, 64);
    float mean = s * (1.0f / 64.0f);
    float d = ka - mean;
    float s2 = d * d;
    for (int off = 32; off; off >>= 1) s2 += __shfl_xor(s2, off, 64);
    float rstd = rsqrtf(s2 * (1.0f / 64.0f) + 1e-5f);
    size_t outi = (size_t)blk * (BATCH * LTXT * 64) + (size_t)bl * 64 + o;
    kbuf[outi] = d * rstd * l2w[blk * 64 + o] + l2b[blk * 64 + o];
    vbuf[outi] = va;
}

// ---------------- ALL 16 attention blocks fused: feat tile resident in LDS
// 512 threads = 64 pixels x 8 heads; cross-attn has no pixel-pixel dataflow,
// so the whole residual chain is per-pixel -> loop layers on-chip.
// Writes final feat directly as NHWC bf16 (X1) for the MFMA convs.
__global__ void __launch_bounds__(512, 2)
attn_all_kernel(const float* __restrict__ feat,
                const float* __restrict__ kbuf, const float* __restrict__ vbuf,
                const float* __restrict__ qw_a, const float* __restrict__ qb_a,
                const float* __restrict__ ow_a, const float* __restrict__ ob_a,
                const float* __restrict__ l1w_a, const float* __restrict__ l1b_a,
                unsigned short* __restrict__ X1) {
    __shared__ float sf[64][64];        // feat tile [c][p]
    __shared__ float so[64][64];        // attn-out exchange [c][p]
    __shared__ float red[2][8][64];     // LN partials

    int b = blockIdx.x >> 6;
    int tile = blockIdx.x & 63;
    int n0 = tile << 6;
    int h = __builtin_amdgcn_readfirstlane(threadIdx.x >> 6);
    int p = threadIdx.x & 63;
    int o0 = h * 8;
    const float* fbase = feat + ((size_t)b << 18) + n0;

    // stage feat tile once (coalesced along p)
    for (int c = h; c < 64; c += 8) sf[c][p] = fbase[c * HW0 + p];

    float px = (float)p * (1.0f / 63.0f);
    float py = (float)tile * (1.0f / 63.0f);
    float pev = 0.05f * ((h < 4) ? px : py);
    const float scale = 0.35355339059327373f;
    __syncthreads();

#pragma unroll 1
    for (int layer = 0; layer < 16; layer++) {
        const float* qw = qw_a + layer * 4096;
        const float* ow = ow_a + layer * 4096;
        const float* qb = qb_a + layer * 64;
        const float* ob = ob_a + layer * 64;
        const float* l1w = l1w_a + layer * 64;
        const float* l1b = l1b_a + layer * 64;

        // q projection for my head's 8 channels
        float q[8];
#pragma unroll
        for (int j = 0; j < 8; j++) q[j] = qb[o0 + j];
#pragma unroll 4
        for (int cc = 0; cc < 64; cc += 4) {
            float f0 = sf[cc][p], f1 = sf[cc+1][p], f2 = sf[cc+2][p], f3 = sf[cc+3][p];
#pragma unroll
            for (int j = 0; j < 8; j++) {
                const float* wr = qw + (o0 + j) * 64 + cc;   // wave-uniform -> s_load
                q[j] += f0 * wr[0] + f1 * wr[1] + f2 * wr[2] + f3 * wr[3];
            }
        }

        float s = 0.f, s2 = 0.f;
#pragma unroll
        for (int j = 0; j < 8; j++) {
            q[j] += pev;
            s += q[j];
            s2 += q[j] * q[j];
        }
        red[0][h][p] = s;
        red[1][h][p] = s2;
        __syncthreads();   // B1

        float ts = 0.f, ts2 = 0.f;
#pragma unroll
        for (int hh = 0; hh < 8; hh++) { ts += red[0][hh][p]; ts2 += red[1][hh][p]; }
        float mean = ts * (1.0f / 64.0f);
        float var = ts2 * (1.0f / 64.0f) - mean * mean;
        float rstd = rsqrtf(var + 1e-5f);
#pragma unroll
        for (int j = 0; j < 8; j++) q[j] = (q[j] - mean) * rstd * l1w[o0 + j] + l1b[o0 + j];

        // cross attention over 77 text tokens (no max subtraction; scores bounded)
        const float* kb_b = kbuf + ((size_t)layer * BATCH * LTXT + (size_t)b * LTXT) * 64 + o0;
        const float* vb_b = vbuf + ((size_t)layer * BATCH * LTXT + (size_t)b * LTXT) * 64 + o0;
        float ssum = 0.f;
        float acc[8] = {0.f,0.f,0.f,0.f,0.f,0.f,0.f,0.f};
        for (int l = 0; l < LTXT; l++) {
            const float4* kr = (const float4*)(kb_b + l * 64);
            float4 k0 = kr[0], k1 = kr[1];
            float sd = q[0]*k0.x + q[1]*k0.y + q[2]*k0.z + q[3]*k0.w
                     + q[4]*k1.x + q[5]*k1.y + q[6]*k1.z + q[7]*k1.w;
            float e = __expf(sd * scale);
            ssum += e;
            const float4* vr = (const float4*)(vb_b + l * 64);
            float4 v0 = vr[0], v1 = vr[1];
            acc[0] += e*v0.x; acc[1] += e*v0.y; acc[2] += e*v0.z; acc[3] += e*v0.w;
            acc[4] += e*v1.x; acc[5] += e*v1.y; acc[6] += e*v1.z; acc[7] += e*v1.w;
        }
        float inv = 1.0f / ssum;
#pragma unroll
        for (int j = 0; j < 8; j++) so[o0 + j][p] = acc[j] * inv;
        __syncthreads();   // B2

        // out projection + residual update in LDS
        float r[8];
#pragma unroll
        for (int j = 0; j < 8; j++) r[j] = ob[o0 + j];
#pragma unroll 4
        for (int cc = 0; cc < 64; cc += 4) {
            float s0 = so[cc][p], s1 = so[cc+1][p], s2v = so[cc+2][p], s3 = so[cc+3][p];
#pragma unroll
            for (int j = 0; j < 8; j++) {
                const float* wr = ow + (o0 + j) * 64 + cc;   // wave-uniform -> s_load
                r[j] += s0 * wr[0] + s1 * wr[1] + s2v * wr[2] + s3 * wr[3];
            }
        }
#pragma unroll
        for (int j = 0; j < 8; j++) sf[o0 + j][p] += r[j];   // thread-owned element
        __syncthreads();   // B3
    }

    // write final feat as NHWC bf16: X1[(b*4096+n)*64 + c]
    us8 v;
#pragma unroll
    for (int j = 0; j < 8; j++) v[j] = f2bf(sf[o0 + j][p]);
    *(us8*)(X1 + ((size_t)(b * 4096 + n0 + p)) * 64 + o0) = v;
}

// ---------------- weight pack: up_w[st] [256co][64ci][9kp] fp32
// -> [9t][2s][4q][256 n'][8j] bf16, n' = c + 64*(2r1+r2), co = 4c+g
__global__ void pack_up_kernel(const float* __restrict__ up_w,
                               unsigned short* __restrict__ PW1,
                               unsigned short* __restrict__ PW2) {
    int e = blockIdx.x * 256 + threadIdx.x;   // < 147456
    const float* w = up_w + (size_t)blockIdx.y * 147456;
    unsigned short* d = blockIdx.y ? PW2 : PW1;
    int j = e & 7, n = (e >> 3) & 255, q = (e >> 11) & 3, s = (e >> 13) & 1, t = e >> 14;
    int c = n & 63, g = n >> 6;
    int co = 4 * c + g, ci = 32 * s + 8 * q + j;
    d[e] = f2bf(w[co * 576 + ci * 9 + t]);
}

// ---------------- weight pack final: cl_w [3][64][9] -> [9][2][4][16][8] (n>=3 zero)
__global__ void pack_final_kernel(const float* __restrict__ cl_w,
                                  unsigned short* __restrict__ PWF) {
    int e = blockIdx.x * 256 + threadIdx.x;   // < 9216
    int j = e & 7, n = (e >> 3) & 15, q = (e >> 7) & 3, s = (e >> 9) & 1, t = e >> 10;
    int ci = 32 * s + 8 * q + j;
    float v = (n < 3) ? cl_w[n * 576 + ci * 9 + t] : 0.f;
    PWF[e] = f2bf(v);
}

// ---------------- upsample conv as 9-tap implicit GEMM, MFMA 16x16x32 bf16
__global__ void __launch_bounds__(256)
upconv_mfma_kernel(const unsigned short* __restrict__ X, const unsigned short* __restrict__ Bp,
                   const float* __restrict__ bias, unsigned short* __restrict__ Y,
                   int Hin, int Win) {
    int wv = threadIdx.x >> 6;
    int lane = threadIdx.x & 63;
    int q = lane >> 4, n16 = lane & 15;
    int m0 = blockIdx.x * 64;
    int hw = Hin * Win;
    int b = m0 / hw, rem = m0 % hw;
    int h = rem / Win, w0 = rem % Win;
    const unsigned short* Xb = X + (size_t)b * hw * 64;

    ffrag acc[4][4];
#pragma unroll
    for (int i = 0; i < 4; i++)
#pragma unroll
        for (int j2 = 0; j2 < 4; j2++) acc[i][j2] = (ffrag)0.f;
    const bfrag zf = (bfrag)(short)0;

    for (int t = 0; t < 9; t++) {
        int dy = t / 3 - 1, dx = t % 3 - 1;
        int hh = h + dy;
        if ((unsigned)hh >= (unsigned)Hin) continue;
        bfrag af[4][2];
#pragma unroll
        for (int mt = 0; mt < 4; mt++) {
            int wp = w0 + mt * 16 + n16 + dx;
            bool ok = (unsigned)wp < (unsigned)Win;
            const unsigned short* src = Xb + ((size_t)hh * Win + wp) * 64 + q * 8;
            af[mt][0] = ok ? *(const bfrag*)src : zf;
            af[mt][1] = ok ? *(const bfrag*)(src + 32) : zf;
        }
#pragma unroll
        for (int s = 0; s < 2; s++) {
#pragma unroll
            for (int nt = 0; nt < 4; nt++) {
                bfrag bf = *(const bfrag*)(Bp + (size_t)((((t * 2 + s) * 4 + q) * 256) + wv * 64 + nt * 16 + n16) * 8);
#pragma unroll
                for (int mt = 0; mt < 4; mt++)
                    acc[mt][nt] = __builtin_amdgcn_mfma_f32_16x16x32_bf16(af[mt][s], bf, acc[mt][nt], 0, 0, 0);
            }
        }
    }

    float bv[4];
#pragma unroll
    for (int nt = 0; nt < 4; nt++) bv[nt] = bias[4 * (nt * 16 + n16) + wv];
    int r1 = wv >> 1, r2 = wv & 1;
    int Wo = Win * 2;
    unsigned short* Yb = Y + ((size_t)b * Hin * 2 * Wo + (size_t)(2 * h + r1) * Wo + r2) * 64;
#pragma unroll
    for (int mt = 0; mt < 4; mt++) {
#pragma unroll
        for (int r = 0; r < 4; r++) {
            int m = mt * 16 + q * 4 + r;   // C/D: row = quad*4 + reg
            unsigned short* dst = Yb + (size_t)(2 * (w0 + m)) * 64;
#pragma unroll
            for (int nt = 0; nt < 4; nt++) {
                float v = acc[mt][nt][r] + bv[nt];
                v = fmaxf(v, 0.f);
                dst[nt * 16 + n16] = f2bf(v);
            }
        }
    }
}

// ---------------- final conv as 9-tap implicit GEMM, N=16 (3 real), fp32 NCHW out
__global__ void __launch_bounds__(256)
final_mfma_kernel(const unsigned short* __restrict__ X, const unsigned short* __restrict__ Bp,
                  const float* __restrict__ bias, float* __restrict__ out) {
    int wv = threadIdx.x >> 6, lane = threadIdx.x & 63;
    int q = lane >> 4, n16 = lane & 15;
    int m0 = blockIdx.x * 256 + wv * 64;
    int b = m0 >> 16;
    int rem = m0 & 65535;
    int h = rem >> 8, w0 = rem & 255;
    const unsigned short* Xb = X + (size_t)b * 65536 * 64;

    ffrag acc[4];
#pragma unroll
    for (int i = 0; i < 4; i++) acc[i] = (ffrag)0.f;
    const bfrag zf = (bfrag)(short)0;

    for (int t = 0; t < 9; t++) {
        int dy = t / 3 - 1, dx = t % 3 - 1;
        int hh = h + dy;
        if ((unsigned)hh >= 256u) continue;
        bfrag af[4][2];
#pragma unroll
        for (int mt = 0; mt < 4; mt++) {
            int wp = w0 + mt * 16 + n16 + dx;
            bool ok = (unsigned)wp < 256u;
            const unsigned short* src = Xb + ((size_t)hh * 256 + wp) * 64 + q * 8;
            af[mt][0] = ok ? *(const bfrag*)src : zf;
            af[mt][1] = ok ? *(const bfrag*)(src + 32) : zf;
        }
#pragma unroll
        for (int s = 0; s < 2; s++) {
            bfrag bf = *(const bfrag*)(Bp + (size_t)((((t * 2 + s) * 4 + q) * 16) + n16) * 8);
#pragma unroll
            for (int mt = 0; mt < 4; mt++)
                acc[mt] = __builtin_amdgcn_mfma_f32_16x16x32_bf16(af[mt][s], bf, acc[mt], 0, 0, 0);
        }
    }

    if (n16 < 3) {
        float bj = bias[n16];
        float* ob = out + (((size_t)b * 3 + n16) * 256 + h) * 256;
#pragma unroll
        for (int mt = 0; mt < 4; mt++)
#pragma unroll
            for (int r = 0; r < 4; r++)
                ob[w0 + mt * 16 + q * 4 + r] = acc[mt][r] + bj;
    }
}

extern "C" void kernel_launch(void* const* d_in, const int* in_sizes, int n_in,
                              void* d_out, int out_size, void* d_ws, size_t ws_size,
                              hipStream_t stream) {
    const float* x      = (const float*)d_in[0];
    const float* th     = (const float*)d_in[1];
    const float* proj_w = (const float*)d_in[2];
    const float* proj_b = (const float*)d_in[3];
    const float* cf_w   = (const float*)d_in[4];
    const float* cf_b   = (const float*)d_in[5];
    const float* qw     = (const float*)d_in[6];
    const float* qb     = (const float*)d_in[7];
    const float* kw     = (const float*)d_in[8];
    const float* kb     = (const float*)d_in[9];
    const float* vw     = (const float*)d_in[10];
    const float* vb     = (const float*)d_in[11];
    const float* ow     = (const float*)d_in[12];
    const float* ob     = (const float*)d_in[13];
    const float* l1w    = (const float*)d_in[14];
    const float* l1b    = (const float*)d_in[15];
    const float* l2w    = (const float*)d_in[16];
    const float* l2b    = (const float*)d_in[17];
    const float* up_w   = (const float*)d_in[18];
    const float* up_b   = (const float*)d_in[19];
    const float* cl_w   = (const float*)d_in[20];
    const float* cl_b   = (const float*)d_in[21];

    float* ws   = (float*)d_ws;
    float* feat = ws;                         // 2,097,152 f
    float* tf   = feat + 2097152;             // 39,424 f
    float* kbuf = tf + 39424;                 // 630,784 f
    float* vbuf = kbuf + 630784;              // 630,784 f
    unsigned short* X1  = (unsigned short*)(vbuf + 630784);  // 2,097,152 us
    unsigned short* X2  = X1 + 2097152;       // 8,388,608 us
    unsigned short* X3  = X2 + 8388608;       // 33,554,432 us
    unsigned short* PW1 = X3 + 33554432;      // 147,456 us
    unsigned short* PW2 = PW1 + 147456;       // 147,456 us
    unsigned short* PWF = PW2 + 147456;       // 9,216 us

    hipLaunchKernelGGL(pack_up_kernel, dim3(576, 2), dim3(256), 0, stream, up_w, PW1, PW2);
    hipLaunchKernelGGL(pack_final_kernel, dim3(36), dim3(256), 0, stream, cl_w, PWF);
    hipLaunchKernelGGL(text_proj_kernel, dim3(BATCH * LTXT), dim3(64), 0, stream,
                       th, proj_w, proj_b, tf);
    hipLaunchKernelGGL(kv_all_kernel, dim3(16 * BATCH * LTXT), dim3(64), 0, stream,
                       tf, kw, kb, vw, vb, l2w, l2b, kbuf, vbuf);
    hipLaunchKernelGGL(conv_in_kernel, dim3((BATCH * C * HW0) / 256), dim3(256), 0, stream,
                       x, cf_w, cf_b, feat);

    hipLaunchKernelGGL(attn_all_kernel, dim3(BATCH * (HW0 / 64)), dim3(512), 0, stream,
                       feat, kbuf, vbuf, qw, qb, ow, ob, l1w, l1b, X1);

    hipLaunchKernelGGL(upconv_mfma_kernel, dim3(BATCH * 64 * 64 / 64), dim3(256), 0, stream,
                       X1, PW1, up_b, X2, 64, 64);
    hipLaunchKernelGGL(upconv_mfma_kernel, dim3(BATCH * 128 * 128 / 64), dim3(256), 0, stream,
                       X2, PW2, up_b + 256, X3, 128, 128);
    hipLaunchKernelGGL(final_mfma_kernel, dim3(BATCH * 256 * 256 / 256), dim3(256), 0, stream,
                       X3, PWF, cl_b, (float*)d_out);
}

// Round 6
// 775.441 us; speedup vs baseline: 14.5983x; 1.3688x over previous
//
#include <hip/hip_runtime.h>
#include <math.h>

#define BATCH 8
#define C 64
#define NH 8
#define HD 8
#define LTXT 77
#define H0 64
#define W0 64
#define HW0 (H0*W0)

typedef __attribute__((ext_vector_type(8))) short bfrag;    // 8 bf16 (4 VGPR)
typedef __attribute__((ext_vector_type(4))) float ffrag;    // 4 fp32 acc
typedef __attribute__((ext_vector_type(8))) unsigned short us8;
typedef __attribute__((ext_vector_type(4))) unsigned short us4;
typedef __attribute__((ext_vector_type(2))) float f2;

__device__ __forceinline__ unsigned short f2bf(float f) {
    unsigned u = __builtin_bit_cast(unsigned, f);
    u += 0x7fff + ((u >> 16) & 1);   // RNE
    return (unsigned short)(u >> 16);
}

// ---------------- text projection: tf[b,l,c] = th[b,l,:] . proj_w[c,:] + proj_b[c]
__global__ void text_proj_kernel(const float* __restrict__ th, const float* __restrict__ pw,
                                 const float* __restrict__ pb, float* __restrict__ tf) {
    __shared__ float sh[512];
    int bl = blockIdx.x;
    int c = threadIdx.x;
    const float* row = th + (size_t)bl * 512;
    for (int i = c; i < 512; i += 64) sh[i] = row[i];
    __syncthreads();
    const float* wrow = pw + c * 512;
    float acc = pb[c];
    for (int i = 0; i < 512; i += 4) {
        acc += sh[i] * wrow[i] + sh[i+1] * wrow[i+1] + sh[i+2] * wrow[i+2] + sh[i+3] * wrow[i+3];
    }
    tf[bl * 64 + c] = acc;
}

// ---------------- first 3x3 conv: x[8,3,64,64] -> feat[8,64,64,64] fp32 NCHW
__global__ void conv_in_kernel(const float* __restrict__ x, const float* __restrict__ w,
                               const float* __restrict__ bias, float* __restrict__ feat) {
    int idx = blockIdx.x * blockDim.x + threadIdx.x;
    if (idx >= BATCH * C * HW0) return;
    int wx = idx & 63;
    int h = (idx >> 6) & 63;
    int o = (idx >> 12) & 63;
    int b = idx >> 18;
    const float* wr = w + o * 27;
    float acc = bias[o];
    for (int ci = 0; ci < 3; ci++) {
        for (int ky = 0; ky < 3; ky++) {
            int y = h + ky - 1;
            if ((unsigned)y >= 64u) continue;
            const float* xr = x + (((size_t)b * 3 + ci) * 64 + y) * 64;
            const float* wk = wr + ci * 9 + ky * 3;
            if (wx > 0) acc += xr[wx - 1] * wk[0];
            acc += xr[wx] * wk[1];
            if (wx < 63) acc += xr[wx + 1] * wk[2];
        }
    }
    feat[idx] = acc;
}

// ---------------- K/V for ALL 16 blocks upfront
__global__ void kv_all_kernel(const float* __restrict__ tf,
                              const float* __restrict__ kw, const float* __restrict__ kb,
                              const float* __restrict__ vw, const float* __restrict__ vb,
                              const float* __restrict__ l2w, const float* __restrict__ l2b,
                              float* __restrict__ kbuf, float* __restrict__ vbuf) {
    __shared__ float sh[64];
    int g = blockIdx.x;
    int bl = g % (BATCH * LTXT);
    int blk = g / (BATCH * LTXT);
    int o = threadIdx.x;
    sh[o] = tf[bl * 64 + o];
    __syncthreads();
    const float* kr = kw + blk * 4096 + o * 64;
    const float* vr = vw + blk * 4096 + o * 64;
    float ka = kb[blk * 64 + o], va = vb[blk * 64 + o];
    for (int c2 = 0; c2 < 64; c2++) {
        float t = sh[c2];
        ka += t * kr[c2];
        va += t * vr[c2];
    }
    float s = ka;
    for (int off = 32; off; off >>= 1) s += __shfl_xor(s, off, 64);
    float mean = s * (1.0f / 64.0f);
    float d = ka - mean;
    float s2 = d * d;
    for (int off = 32; off; off >>= 1) s2 += __shfl_xor(s2, off, 64);
    float rstd = rsqrtf(s2 * (1.0f / 64.0f) + 1e-5f);
    size_t outi = (size_t)blk * (BATCH * LTXT * 64) + (size_t)bl * 64 + o;
    kbuf[outi] = d * rstd * l2w[blk * 64 + o] + l2b[blk * 64 + o];
    vbuf[outi] = va;
}

// ---------------- ALL 16 attention blocks fused, 1024 threads = 16 waves.
// Projections: wave w owns 4 output channels (wave-uniform weights -> s_load).
// Attention:   wave w = (head h=w>>1, token-half=w&1); no-max softmax is a pure
//              sum so the two halves merge with one add.
// Residual feat tile lives in LDS fp32; final write is NHWC bf16.
__global__ void __launch_bounds__(1024, 8)
attn_all_kernel(const float* __restrict__ feat,
                const float* __restrict__ kbuf, const float* __restrict__ vbuf,
                const float* __restrict__ qw_a, const float* __restrict__ qb_a,
                const float* __restrict__ ow_a, const float* __restrict__ ob_a,
                const float* __restrict__ l1w_a, const float* __restrict__ l1b_a,
                unsigned short* __restrict__ X1) {
    __shared__ float sf[64][64];        // residual feat tile [c][p]
    __shared__ float qn[64][64];        // normalized q [c][p]
    __shared__ float so[64][64];        // attn-out exchange [c][p]
    __shared__ float red[2][16][64];    // LN partials [sum/sumsq][wave][p]
    __shared__ float ss1[8][64];        // half-1 softmax denominators [h][p]

    int b = blockIdx.x >> 6;
    int tile = blockIdx.x & 63;
    int n0 = tile << 6;
    int w = __builtin_amdgcn_readfirstlane(threadIdx.x >> 6);  // wave 0..15
    int p = threadIdx.x & 63;
    int o0 = w * 4;                  // projection channels o0..o0+3
    int h = w >> 1, half = w & 1;    // attention role
    int a0 = h * 8;
    const float* fbase = feat + ((size_t)b << 18) + n0;

    // stage feat tile (coalesced along p)
#pragma unroll
    for (int j = 0; j < 4; j++) sf[o0 + j][p] = fbase[(o0 + j) * HW0 + p];

    float px = (float)p * (1.0f / 63.0f);
    float py = (float)tile * (1.0f / 63.0f);
    float pev = 0.05f * ((w < 8) ? px : py);   // o0..o0+3 all <32 iff w<8
    const float scale = 0.35355339059327373f;
    __syncthreads();

#pragma unroll 1
    for (int layer = 0; layer < 16; layer++) {
        const float* qw = qw_a + layer * 4096;
        const float* ow = ow_a + layer * 4096;
        const float* qb = qb_a + layer * 64;
        const float* ob = ob_a + layer * 64;
        const float* l1w = l1w_a + layer * 64;
        const float* l1b = l1b_a + layer * 64;

        // ---- A: q projection, 4 channels per thread
        float q[4];
#pragma unroll
        for (int j = 0; j < 4; j++) q[j] = qb[o0 + j];
#pragma unroll 4
        for (int cc = 0; cc < 64; cc += 4) {
            float f0 = sf[cc][p], f1 = sf[cc+1][p], f2v = sf[cc+2][p], f3 = sf[cc+3][p];
#pragma unroll
            for (int j = 0; j < 4; j++) {
                const float* wr = qw + (o0 + j) * 64 + cc;   // wave-uniform -> s_load
                q[j] += f0 * wr[0] + f1 * wr[1] + f2v * wr[2] + f3 * wr[3];
            }
        }
        float s = 0.f, s2 = 0.f;
#pragma unroll
        for (int j = 0; j < 4; j++) {
            q[j] += pev;
            s += q[j];
            s2 += q[j] * q[j];
        }
        red[0][w][p] = s;
        red[1][w][p] = s2;
        __syncthreads();   // B1

        // ---- B: LN stats + write normalized q
        float ts = 0.f, ts2 = 0.f;
#pragma unroll
        for (int k = 0; k < 16; k++) { ts += red[0][k][p]; ts2 += red[1][k][p]; }
        float mean = ts * (1.0f / 64.0f);
        float var = ts2 * (1.0f / 64.0f) - mean * mean;
        float rstd = rsqrtf(var + 1e-5f);
#pragma unroll
        for (int j = 0; j < 4; j++)
            qn[o0 + j][p] = (q[j] - mean) * rstd * l1w[o0 + j] + l1b[o0 + j];
        __syncthreads();   // B2

        // ---- C: attention, wave = (head, token-half)
        f2 qv[4];
#pragma unroll
        for (int j = 0; j < 4; j++) {
            qv[j][0] = qn[a0 + 2*j][p];
            qv[j][1] = qn[a0 + 2*j + 1][p];
        }
        const float* kb_b = kbuf + ((size_t)layer * BATCH * LTXT + (size_t)b * LTXT) * 64 + a0;
        const float* vb_b = vbuf + ((size_t)layer * BATCH * LTXT + (size_t)b * LTXT) * 64 + a0;
        int l0 = half ? 39 : 0;
        int l1 = half ? 77 : 39;
        float ssum = 0.f;
        f2 acc2[4] = {(f2)0.f, (f2)0.f, (f2)0.f, (f2)0.f};
        for (int l = l0; l < l1; l++) {
            const f2* kr = (const f2*)(kb_b + l * 64);   // wave-uniform -> s_load
            f2 sd2 = qv[0] * kr[0];
            sd2 += qv[1] * kr[1];
            sd2 += qv[2] * kr[2];
            sd2 += qv[3] * kr[3];
            float e = __expf((sd2[0] + sd2[1]) * scale);
            ssum += e;
            const f2* vr = (const f2*)(vb_b + l * 64);
            f2 e2 = {e, e};
            acc2[0] += e2 * vr[0];
            acc2[1] += e2 * vr[1];
            acc2[2] += e2 * vr[2];
            acc2[3] += e2 * vr[3];
        }
        if (half) {
#pragma unroll
            for (int j = 0; j < 4; j++) {
                so[a0 + 2*j][p] = acc2[j][0];
                so[a0 + 2*j + 1][p] = acc2[j][1];
            }
            ss1[h][p] = ssum;
        }
        __syncthreads();   // B3
        if (!half) {
            float inv = 1.0f / (ssum + ss1[h][p]);
#pragma unroll
            for (int j = 0; j < 4; j++) {
                so[a0 + 2*j][p] = (acc2[j][0] + so[a0 + 2*j][p]) * inv;
                so[a0 + 2*j + 1][p] = (acc2[j][1] + so[a0 + 2*j + 1][p]) * inv;
            }
        }
        __syncthreads();   // B4

        // ---- D: out projection + residual, 4 channels per thread
        float r[4];
#pragma unroll
        for (int j = 0; j < 4; j++) r[j] = ob[o0 + j];
#pragma unroll 4
        for (int cc = 0; cc < 64; cc += 4) {
            float s0 = so[cc][p], s1 = so[cc+1][p], s2v = so[cc+2][p], s3 = so[cc+3][p];
#pragma unroll
            for (int j = 0; j < 4; j++) {
                const float* wr = ow + (o0 + j) * 64 + cc;   // wave-uniform -> s_load
                r[j] += s0 * wr[0] + s1 * wr[1] + s2v * wr[2] + s3 * wr[3];
            }
        }
#pragma unroll
        for (int j = 0; j < 4; j++) sf[o0 + j][p] += r[j];   // exclusive owner
        __syncthreads();   // B5
    }

    // final write: NHWC bf16, 4 contiguous channels per thread
    us4 v;
#pragma unroll
    for (int j = 0; j < 4; j++) v[j] = f2bf(sf[o0 + j][p]);
    *(us4*)(X1 + ((size_t)(b * 4096 + n0 + p)) * 64 + o0) = v;
}

// ---------------- weight pack: up_w[st] [256co][64ci][9kp] fp32
// -> [9t][2s][4q][256 n'][8j] bf16, n' = c + 64*(2r1+r2), co = 4c+g
__global__ void pack_up_kernel(const float* __restrict__ up_w,
                               unsigned short* __restrict__ PW1,
                               unsigned short* __restrict__ PW2) {
    int e = blockIdx.x * 256 + threadIdx.x;   // < 147456
    const float* w = up_w + (size_t)blockIdx.y * 147456;
    unsigned short* d = blockIdx.y ? PW2 : PW1;
    int j = e & 7, n = (e >> 3) & 255, q = (e >> 11) & 3, s = (e >> 13) & 1, t = e >> 14;
    int c = n & 63, g = n >> 6;
    int co = 4 * c + g, ci = 32 * s + 8 * q + j;
    d[e] = f2bf(w[co * 576 + ci * 9 + t]);
}

// ---------------- weight pack final: cl_w [3][64][9] -> [9][2][4][16][8] (n>=3 zero)
__global__ void pack_final_kernel(const float* __restrict__ cl_w,
                                  unsigned short* __restrict__ PWF) {
    int e = blockIdx.x * 256 + threadIdx.x;   // < 9216
    int j = e & 7, n = (e >> 3) & 15, q = (e >> 7) & 3, s = (e >> 9) & 1, t = e >> 10;
    int ci = 32 * s + 8 * q + j;
    float v = (n < 3) ? cl_w[n * 576 + ci * 9 + t] : 0.f;
    PWF[e] = f2bf(v);
}

// ---------------- upsample conv as 9-tap implicit GEMM, MFMA 16x16x32 bf16
__global__ void __launch_bounds__(256)
upconv_mfma_kernel(const unsigned short* __restrict__ X, const unsigned short* __restrict__ Bp,
                   const float* __restrict__ bias, unsigned short* __restrict__ Y,
                   int Hin, int Win) {
    int wv = threadIdx.x >> 6;
    int lane = threadIdx.x & 63;
    int q = lane >> 4, n16 = lane & 15;
    int m0 = blockIdx.x * 64;
    int hw = Hin * Win;
    int b = m0 / hw, rem = m0 % hw;
    int h = rem / Win, w0 = rem % Win;
    const unsigned short* Xb = X + (size_t)b * hw * 64;

    ffrag acc[4][4];
#pragma unroll
    for (int i = 0; i < 4; i++)
#pragma unroll
        for (int j2 = 0; j2 < 4; j2++) acc[i][j2] = (ffrag)0.f;
    const bfrag zf = (bfrag)(short)0;

    for (int t = 0; t < 9; t++) {
        int dy = t / 3 - 1, dx = t % 3 - 1;
        int hh = h + dy;
        if ((unsigned)hh >= (unsigned)Hin) continue;
        bfrag af[4][2];
#pragma unroll
        for (int mt = 0; mt < 4; mt++) {
            int wp = w0 + mt * 16 + n16 + dx;
            bool ok = (unsigned)wp < (unsigned)Win;
            const unsigned short* src = Xb + ((size_t)hh * Win + wp) * 64 + q * 8;
            af[mt][0] = ok ? *(const bfrag*)src : zf;
            af[mt][1] = ok ? *(const bfrag*)(src + 32) : zf;
        }
#pragma unroll
        for (int s = 0; s < 2; s++) {
#pragma unroll
            for (int nt = 0; nt < 4; nt++) {
                bfrag bf = *(const bfrag*)(Bp + (size_t)((((t * 2 + s) * 4 + q) * 256) + wv * 64 + nt * 16 + n16) * 8);
#pragma unroll
                for (int mt = 0; mt < 4; mt++)
                    acc[mt][nt] = __builtin_amdgcn_mfma_f32_16x16x32_bf16(af[mt][s], bf, acc[mt][nt], 0, 0, 0);
            }
        }
    }

    float bv[4];
#pragma unroll
    for (int nt = 0; nt < 4; nt++) bv[nt] = bias[4 * (nt * 16 + n16) + wv];
    int r1 = wv >> 1, r2 = wv & 1;
    int Wo = Win * 2;
    unsigned short* Yb = Y + ((size_t)b * Hin * 2 * Wo + (size_t)(2 * h + r1) * Wo + r2) * 64;
#pragma unroll
    for (int mt = 0; mt < 4; mt++) {
#pragma unroll
        for (int r = 0; r < 4; r++) {
            int m = mt * 16 + q * 4 + r;   // C/D: row = quad*4 + reg
            unsigned short* dst = Yb + (size_t)(2 * (w0 + m)) * 64;
#pragma unroll
            for (int nt = 0; nt < 4; nt++) {
                float v = acc[mt][nt][r] + bv[nt];
                v = fmaxf(v, 0.f);
                dst[nt * 16 + n16] = f2bf(v);
            }
        }
    }
}

// ---------------- final conv as 9-tap implicit GEMM, N=16 (3 real), fp32 NCHW out
__global__ void __launch_bounds__(256)
final_mfma_kernel(const unsigned short* __restrict__ X, const unsigned short* __restrict__ Bp,
                  const float* __restrict__ bias, float* __restrict__ out) {
    int wv = threadIdx.x >> 6, lane = threadIdx.x & 63;
    int q = lane >> 4, n16 = lane & 15;
    int m0 = blockIdx.x * 256 + wv * 64;
    int b = m0 >> 16;
    int rem = m0 & 65535;
    int h = rem >> 8, w0 = rem & 255;
    const unsigned short* Xb = X + (size_t)b * 65536 * 64;

    ffrag acc[4];
#pragma unroll
    for (int i = 0; i < 4; i++) acc[i] = (ffrag)0.f;
    const bfrag zf = (bfrag)(short)0;

    for (int t = 0; t < 9; t++) {
        int dy = t / 3 - 1, dx = t % 3 - 1;
        int hh = h + dy;
        if ((unsigned)hh >= 256u) continue;
        bfrag af[4][2];
#pragma unroll
        for (int mt = 0; mt < 4; mt++) {
            int wp = w0 + mt * 16 + n16 + dx;
            bool ok = (unsigned)wp < 256u;
            const unsigned short* src = Xb + ((size_t)hh * 256 + wp) * 64 + q * 8;
            af[mt][0] = ok ? *(const bfrag*)src : zf;
            af[mt][1] = ok ? *(const bfrag*)(src + 32) : zf;
        }
#pragma unroll
        for (int s = 0; s < 2; s++) {
            bfrag bf = *(const bfrag*)(Bp + (size_t)((((t * 2 + s) * 4 + q) * 16) + n16) * 8);
#pragma unroll
            for (int mt = 0; mt < 4; mt++)
                acc[mt] = __builtin_amdgcn_mfma_f32_16x16x32_bf16(af[mt][s], bf, acc[mt], 0, 0, 0);
        }
    }

    if (n16 < 3) {
        float bj = bias[n16];
        float* ob = out + (((size_t)b * 3 + n16) * 256 + h) * 256;
#pragma unroll
        for (int mt = 0; mt < 4; mt++)
#pragma unroll
            for (int r = 0; r < 4; r++)
                ob[w0 + mt * 16 + q * 4 + r] = acc[mt][r] + bj;
    }
}

extern "C" void kernel_launch(void* const* d_in, const int* in_sizes, int n_in,
                              void* d_out, int out_size, void* d_ws, size_t ws_size,
                              hipStream_t stream) {
    const float* x      = (const float*)d_in[0];
    const float* th     = (const float*)d_in[1];
    const float* proj_w = (const float*)d_in[2];
    const float* proj_b = (const float*)d_in[3];
    const float* cf_w   = (const float*)d_in[4];
    const float* cf_b   = (const float*)d_in[5];
    const float* qw     = (const float*)d_in[6];
    const float* qb     = (const float*)d_in[7];
    const float* kw     = (const float*)d_in[8];
    const float* kb     = (const float*)d_in[9];
    const float* vw     = (const float*)d_in[10];
    const float* vb     = (const float*)d_in[11];
    const float* ow     = (const float*)d_in[12];
    const float* ob     = (const float*)d_in[13];
    const float* l1w    = (const float*)d_in[14];
    const float* l1b    = (const float*)d_in[15];
    const float* l2w    = (const float*)d_in[16];
    const float* l2b    = (const float*)d_in[17];
    const float* up_w   = (const float*)d_in[18];
    const float* up_b   = (const float*)d_in[19];
    const float* cl_w   = (const float*)d_in[20];
    const float* cl_b   = (const float*)d_in[21];

    float* ws   = (float*)d_ws;
    float* feat = ws;                         // 2,097,152 f
    float* tf   = feat + 2097152;             // 39,424 f
    float* kbuf = tf + 39424;                 // 630,784 f
    float* vbuf = kbuf + 630784;              // 630,784 f
    unsigned short* X1  = (unsigned short*)(vbuf + 630784);  // 2,097,152 us
    unsigned short* X2  = X1 + 2097152;       // 8,388,608 us
    unsigned short* X3  = X2 + 8388608;       // 33,554,432 us
    unsigned short* PW1 = X3 + 33554432;      // 147,456 us
    unsigned short* PW2 = PW1 + 147456;       // 147,456 us
    unsigned short* PWF = PW2 + 147456;       // 9,216 us

    hipLaunchKernelGGL(pack_up_kernel, dim3(576, 2), dim3(256), 0, stream, up_w, PW1, PW2);
    hipLaunchKernelGGL(pack_final_kernel, dim3(36), dim3(256), 0, stream, cl_w, PWF);
    hipLaunchKernelGGL(text_proj_kernel, dim3(BATCH * LTXT), dim3(64), 0, stream,
                       th, proj_w, proj_b, tf);
    hipLaunchKernelGGL(kv_all_kernel, dim3(16 * BATCH * LTXT), dim3(64), 0, stream,
                       tf, kw, kb, vw, vb, l2w, l2b, kbuf, vbuf);
    hipLaunchKernelGGL(conv_in_kernel, dim3((BATCH * C * HW0) / 256), dim3(256), 0, stream,
                       x, cf_w, cf_b, feat);

    hipLaunchKernelGGL(attn_all_kernel, dim3(BATCH * (HW0 / 64)), dim3(1024), 0, stream,
                       feat, kbuf, vbuf, qw, qb, ow, ob, l1w, l1b, X1);

    hipLaunchKernelGGL(upconv_mfma_kernel, dim3(BATCH * 64 * 64 / 64), dim3(256), 0, stream,
                       X1, PW1, up_b, X2, 64, 64);
    hipLaunchKernelGGL(upconv_mfma_kernel, dim3(BATCH * 128 * 128 / 64), dim3(256), 0, stream,
                       X2, PW2, up_b + 256, X3, 128, 128);
    hipLaunchKernelGGL(final_mfma_kernel, dim3(BATCH * 256 * 256 / 256), dim3(256), 0, stream,
                       X3, PWF, cl_b, (float*)d_out);
}

// Round 8
// 677.973 us; speedup vs baseline: 16.6971x; 1.1438x over previous
//
#include <hip/hip_runtime.h>
#include <math.h>

#define BATCH 8
#define C 64
#define NH 8
#define HD 8
#define LTXT 77
#define H0 64
#define W0 64
#define HW0 (H0*W0)

typedef __attribute__((ext_vector_type(8))) short bfrag;    // 8 bf16 (4 VGPR)
typedef __attribute__((ext_vector_type(4))) float ffrag;    // 4 fp32 acc
typedef __attribute__((ext_vector_type(8))) unsigned short us8;
typedef __attribute__((ext_vector_type(4))) unsigned short us4;

__device__ __forceinline__ unsigned short f2bf(float f) {
    unsigned u = __builtin_bit_cast(unsigned, f);
    u += 0x7fff + ((u >> 16) & 1);   // RNE
    return (unsigned short)(u >> 16);
}

// ---------------- text projection: tf[b,l,c] = th[b,l,:] . proj_w[c,:] + proj_b[c]
__global__ void text_proj_kernel(const float* __restrict__ th, const float* __restrict__ pw,
                                 const float* __restrict__ pb, float* __restrict__ tf) {
    __shared__ float sh[512];
    int bl = blockIdx.x;
    int c = threadIdx.x;
    const float* row = th + (size_t)bl * 512;
    for (int i = c; i < 512; i += 64) sh[i] = row[i];
    __syncthreads();
    const float* wrow = pw + c * 512;
    float acc = pb[c];
    for (int i = 0; i < 512; i += 4) {
        acc += sh[i] * wrow[i] + sh[i+1] * wrow[i+1] + sh[i+2] * wrow[i+2] + sh[i+3] * wrow[i+3];
    }
    tf[bl * 64 + c] = acc;
}

// ---------------- first 3x3 conv: x[8,3,64,64] -> feat[8,64,64,64] fp32 NCHW
__global__ void conv_in_kernel(const float* __restrict__ x, const float* __restrict__ w,
                               const float* __restrict__ bias, float* __restrict__ feat) {
    int idx = blockIdx.x * blockDim.x + threadIdx.x;
    if (idx >= BATCH * C * HW0) return;
    int wx = idx & 63;
    int h = (idx >> 6) & 63;
    int o = (idx >> 12) & 63;
    int b = idx >> 18;
    const float* wr = w + o * 27;
    float acc = bias[o];
    for (int ci = 0; ci < 3; ci++) {
        for (int ky = 0; ky < 3; ky++) {
            int y = h + ky - 1;
            if ((unsigned)y >= 64u) continue;
            const float* xr = x + (((size_t)b * 3 + ci) * 64 + y) * 64;
            const float* wk = wr + ci * 9 + ky * 3;
            if (wx > 0) acc += xr[wx - 1] * wk[0];
            acc += xr[wx] * wk[1];
            if (wx < 63) acc += xr[wx + 1] * wk[2];
        }
    }
    feat[idx] = acc;
}

// ---------------- K/V for ALL 16 blocks upfront; K pre-scaled by scale*log2(e)
__global__ void kv_all_kernel(const float* __restrict__ tf,
                              const float* __restrict__ kw, const float* __restrict__ kb,
                              const float* __restrict__ vw, const float* __restrict__ vb,
                              const float* __restrict__ l2w, const float* __restrict__ l2b,
                              float* __restrict__ kbuf, float* __restrict__ vbuf) {
    __shared__ float sh[64];
    int g = blockIdx.x;
    int bl = g % (BATCH * LTXT);
    int blk = g / (BATCH * LTXT);
    int o = threadIdx.x;
    sh[o] = tf[bl * 64 + o];
    __syncthreads();
    const float* kr = kw + blk * 4096 + o * 64;
    const float* vr = vw + blk * 4096 + o * 64;
    float ka = kb[blk * 64 + o], va = vb[blk * 64 + o];
    for (int c2 = 0; c2 < 64; c2++) {
        float t = sh[c2];
        ka += t * kr[c2];
        va += t * vr[c2];
    }
    float s = ka;
    for (int off = 32; off; off >>= 1) s += __shfl_xor(s, off, 64);
    float mean = s * (1.0f / 64.0f);
    float d = ka - mean;
    float s2 = d * d;
    for (int off = 32; off; off >>= 1) s2 += __shfl_xor(s2, off, 64);
    float rstd = rsqrtf(s2 * (1.0f / 64.0f) + 1e-5f);
    size_t outi = (size_t)blk * (BATCH * LTXT * 64) + (size_t)bl * 64 + o;
    // fold softmax scale (1/sqrt(8)) * log2(e) into K so attention uses exp2
    kbuf[outi] = (d * rstd * l2w[blk * 64 + o] + l2b[blk * 64 + o]) * 0.51006973f;
    vbuf[outi] = va;
}

// ---------------- proj weight pack: qw/ow [16][64n][64c] -> [16][kt2][quad4][64n][8j] bf16
__global__ void pack_proj_kernel(const float* __restrict__ qw, const float* __restrict__ ow,
                                 unsigned short* __restrict__ PQ, unsigned short* __restrict__ PO) {
    int e = blockIdx.x * 256 + threadIdx.x;   // < 65536
    int j = e & 7, n = (e >> 3) & 63, quad = (e >> 9) & 3, kt = (e >> 11) & 1, layer = e >> 12;
    int c = kt * 32 + quad * 8 + j;
    PQ[e] = f2bf(qw[layer * 4096 + n * 64 + c]);
    PO[e] = f2bf(ow[layer * 4096 + n * 64 + c]);
}

// ---------------- ALL 16 attention blocks fused, 1024 threads = 16 waves.
// q-proj/out-proj via MFMA (A from bf16 LDS mirror, B from packed global weights);
// attention (QK^T, softmax, PV) on VALU with wave-uniform s_load K/V.
// Residual fp32 lives in registers (4 ch per thread). Output NHWC bf16.
__global__ void __launch_bounds__(1024, 8)
attn_all_kernel(const float* __restrict__ feat,
                const float* __restrict__ kbuf, const float* __restrict__ vbuf,
                const unsigned short* __restrict__ PQ, const unsigned short* __restrict__ PO,
                const float* __restrict__ qb_a, const float* __restrict__ ob_a,
                const float* __restrict__ l1w_a, const float* __restrict__ l1b_a,
                unsigned short* __restrict__ X1) {
    __shared__ __attribute__((aligned(16))) unsigned short sfb[64][72]; // residual bf16 [p][c]
    __shared__ __attribute__((aligned(16))) unsigned short sob[64][72]; // attn-out bf16 [p][c]
    __shared__ __attribute__((aligned(16))) float qf[64][68];           // q / qn / out-proj [c][p]
    __shared__ float so[64][64];        // attn-out fp32 exchange [c][p]
    __shared__ float red[2][16][64];    // LN partials
    __shared__ float ss1[8][64];        // half-1 softmax denominators

    int b = blockIdx.x >> 6;
    int tile = blockIdx.x & 63;
    int n0 = tile << 6;
    int wv = __builtin_amdgcn_readfirstlane(threadIdx.x >> 6);  // wave 0..15
    int lane = threadIdx.x & 63;
    int p = lane;
    int quad = lane >> 4, n16 = lane & 15;
    int mt = wv >> 2, nt = wv & 3;      // GEMM C-tile role
    int o0 = wv * 4;                    // ownership role: channels o0..o0+3, pixel p
    int h = wv >> 1, half = wv & 1;     // attention role
    int a0 = h * 8;
    const float* fbase = feat + ((size_t)b << 18) + n0;

    // stage: residual regs + bf16 mirror
    float rres[4];
#pragma unroll
    for (int j = 0; j < 4; j++) rres[j] = fbase[(o0 + j) * HW0 + p];
    {
        us4 v;
#pragma unroll
        for (int j = 0; j < 4; j++) v[j] = f2bf(rres[j]);
        *(us4*)&sfb[p][o0] = v;
    }

    const float pxk = 0.05f / 63.0f;
    float py005 = (float)tile * pxk;
    __syncthreads();

#pragma unroll 1
    for (int layer = 0; layer < 16; layer++) {
        const float* qb = qb_a + layer * 64;
        const float* ob = ob_a + layer * 64;
        const float* l1w = l1w_a + layer * 64;
        const float* l1b = l1b_a + layer * 64;

        // ---- A: q-proj GEMM, wave = C-tile (mt,nt)
        {
            bfrag af0 = *(const bfrag*)&sfb[mt * 16 + n16][quad * 8];
            bfrag af1 = *(const bfrag*)&sfb[mt * 16 + n16][32 + quad * 8];
            const unsigned short* bq = PQ + layer * 4096 + (size_t)((quad * 64) + nt * 16 + n16) * 8;
            bfrag bf0 = *(const bfrag*)bq;
            bfrag bf1 = *(const bfrag*)(bq + 2048);   // kt=1 chunk (FIXED: was +16384)
            ffrag cc = (ffrag)0.f;
            cc = __builtin_amdgcn_mfma_f32_16x16x32_bf16(af0, bf0, cc, 0, 0, 0);
            cc = __builtin_amdgcn_mfma_f32_16x16x32_bf16(af1, bf1, cc, 0, 0, 0);
            int cch = nt * 16 + n16;
            float qbv = qb[cch];
            int p0 = mt * 16 + quad * 4;
            float pe0 = (nt < 2) ? (float)p0 * pxk : py005;
            float ped = (nt < 2) ? pxk : 0.f;
            float4 o4;
            o4.x = cc[0] + qbv + pe0;
            o4.y = cc[1] + qbv + pe0 + ped;
            o4.z = cc[2] + qbv + pe0 + 2.f * ped;
            o4.w = cc[3] + qbv + pe0 + 3.f * ped;
            *(float4*)&qf[cch][p0] = o4;
        }
        __syncthreads();   // B1

        // ---- B: LN over channels (per pixel)
        float qv4[4];
        {
            float s = 0.f, s2 = 0.f;
#pragma unroll
            for (int j = 0; j < 4; j++) {
                qv4[j] = qf[o0 + j][p];
                s += qv4[j];
                s2 += qv4[j] * qv4[j];
            }
            red[0][wv][p] = s;
            red[1][wv][p] = s2;
        }
        __syncthreads();   // B2
        {
            float ts = 0.f, ts2 = 0.f;
#pragma unroll
            for (int k = 0; k < 16; k++) { ts += red[0][k][p]; ts2 += red[1][k][p]; }
            float mean = ts * (1.0f / 64.0f);
            float var = ts2 * (1.0f / 64.0f) - mean * mean;
            float rstd = rsqrtf(var + 1e-5f);
#pragma unroll
            for (int j = 0; j < 4; j++)
                qf[o0 + j][p] = (qv4[j] - mean) * rstd * l1w[o0 + j] + l1b[o0 + j];
        }
        __syncthreads();   // B3

        // ---- C: attention, wave = (head, token-half); K pre-scaled for exp2
        {
            float q[8];
#pragma unroll
            for (int j = 0; j < 8; j++) q[j] = qf[a0 + j][p];
            const float* kb_b = kbuf + ((size_t)layer * BATCH * LTXT + (size_t)b * LTXT) * 64 + a0;
            const float* vb_b = vbuf + ((size_t)layer * BATCH * LTXT + (size_t)b * LTXT) * 64 + a0;
            int l0 = half ? 39 : 0;
            int l1 = half ? 77 : 39;
            float ssum = 0.f;
            float acc[8] = {0.f,0.f,0.f,0.f,0.f,0.f,0.f,0.f};
            for (int l = l0; l < l1; l++) {
                const float* kr = kb_b + l * 64;   // wave-uniform -> s_load
                float dot = q[0]*kr[0] + q[1]*kr[1] + q[2]*kr[2] + q[3]*kr[3]
                          + q[4]*kr[4] + q[5]*kr[5] + q[6]*kr[6] + q[7]*kr[7];
                float e = exp2f(dot);
                ssum += e;
                const float* vr = vb_b + l * 64;   // wave-uniform -> s_load
#pragma unroll
                for (int d = 0; d < 8; d++) acc[d] += e * vr[d];
            }
            if (half) {
#pragma unroll
                for (int j = 0; j < 8; j++) so[a0 + j][p] = acc[j];
                ss1[h][p] = ssum;
            }
            __syncthreads();   // B4
            if (!half) {
                float inv = 1.0f / (ssum + ss1[h][p]);
                us8 v;
#pragma unroll
                for (int j = 0; j < 8; j++) v[j] = f2bf((acc[j] + so[a0 + j][p]) * inv);
                *(us8*)&sob[p][a0] = v;
            }
        }
        __syncthreads();   // B5

        // ---- D: out-proj GEMM (A from sob), result -> qf (reused as scratch)
        {
            bfrag af0 = *(const bfrag*)&sob[mt * 16 + n16][quad * 8];
            bfrag af1 = *(const bfrag*)&sob[mt * 16 + n16][32 + quad * 8];
            const unsigned short* bo = PO + layer * 4096 + (size_t)((quad * 64) + nt * 16 + n16) * 8;
            bfrag bf0 = *(const bfrag*)bo;
            bfrag bf1 = *(const bfrag*)(bo + 2048);
            ffrag cc = (ffrag)0.f;
            cc = __builtin_amdgcn_mfma_f32_16x16x32_bf16(af0, bf0, cc, 0, 0, 0);
            cc = __builtin_amdgcn_mfma_f32_16x16x32_bf16(af1, bf1, cc, 0, 0, 0);
            int cch = nt * 16 + n16;
            float obv = ob[cch];
            int p0 = mt * 16 + quad * 4;
            float4 o4;
            o4.x = cc[0] + obv; o4.y = cc[1] + obv; o4.z = cc[2] + obv; o4.w = cc[3] + obv;
            *(float4*)&qf[cch][p0] = o4;
        }
        __syncthreads();   // B6

        // ---- E: residual update in regs + refresh bf16 mirror
        {
            us4 v;
#pragma unroll
            for (int j = 0; j < 4; j++) {
                rres[j] += qf[o0 + j][p];
                v[j] = f2bf(rres[j]);
            }
            *(us4*)&sfb[p][o0] = v;
        }
        __syncthreads();   // B7
    }

    // final write: NHWC bf16
    us4 v;
#pragma unroll
    for (int j = 0; j < 4; j++) v[j] = f2bf(rres[j]);
    *(us4*)(X1 + ((size_t)(b * 4096 + n0 + p)) * 64 + o0) = v;
}

// ---------------- weight pack: up_w[st] [256co][64ci][9kp] fp32
// -> [9t][2s][4q][256 n'][8j] bf16, n' = c + 64*(2r1+r2), co = 4c+g
__global__ void pack_up_kernel(const float* __restrict__ up_w,
                               unsigned short* __restrict__ PW1,
                               unsigned short* __restrict__ PW2) {
    int e = blockIdx.x * 256 + threadIdx.x;   // < 147456
    const float* w = up_w + (size_t)blockIdx.y * 147456;
    unsigned short* d = blockIdx.y ? PW2 : PW1;
    int j = e & 7, n = (e >> 3) & 255, q = (e >> 11) & 3, s = (e >> 13) & 1, t = e >> 14;
    int c = n & 63, g = n >> 6;
    int co = 4 * c + g, ci = 32 * s + 8 * q + j;
    d[e] = f2bf(w[co * 576 + ci * 9 + t]);
}

// ---------------- weight pack final: cl_w [3][64][9] -> [9][2][4][16][8] (n>=3 zero)
__global__ void pack_final_kernel(const float* __restrict__ cl_w,
                                  unsigned short* __restrict__ PWF) {
    int e = blockIdx.x * 256 + threadIdx.x;   // < 9216
    int j = e & 7, n = (e >> 3) & 15, q = (e >> 7) & 3, s = (e >> 9) & 1, t = e >> 10;
    int ci = 32 * s + 8 * q + j;
    float v = (n < 3) ? cl_w[n * 576 + ci * 9 + t] : 0.f;
    PWF[e] = f2bf(v);
}

// ---------------- upsample conv as 9-tap implicit GEMM, MFMA 16x16x32 bf16
__global__ void __launch_bounds__(256)
upconv_mfma_kernel(const unsigned short* __restrict__ X, const unsigned short* __restrict__ Bp,
                   const float* __restrict__ bias, unsigned short* __restrict__ Y,
                   int Hin, int Win) {
    int wv = threadIdx.x >> 6;
    int lane = threadIdx.x & 63;
    int q = lane >> 4, n16 = lane & 15;
    int m0 = blockIdx.x * 64;
    int hw = Hin * Win;
    int b = m0 / hw, rem = m0 % hw;
    int h = rem / Win, w0 = rem % Win;
    const unsigned short* Xb = X + (size_t)b * hw * 64;

    ffrag acc[4][4];
#pragma unroll
    for (int i = 0; i < 4; i++)
#pragma unroll
        for (int j2 = 0; j2 < 4; j2++) acc[i][j2] = (ffrag)0.f;
    const bfrag zf = (bfrag)(short)0;

    for (int t = 0; t < 9; t++) {
        int dy = t / 3 - 1, dx = t % 3 - 1;
        int hh = h + dy;
        if ((unsigned)hh >= (unsigned)Hin) continue;
        bfrag af[4][2];
#pragma unroll
        for (int mt = 0; mt < 4; mt++) {
            int wp = w0 + mt * 16 + n16 + dx;
            bool ok = (unsigned)wp < (unsigned)Win;
            const unsigned short* src = Xb + ((size_t)hh * Win + wp) * 64 + q * 8;
            af[mt][0] = ok ? *(const bfrag*)src : zf;
            af[mt][1] = ok ? *(const bfrag*)(src + 32) : zf;
        }
#pragma unroll
        for (int s = 0; s < 2; s++) {
#pragma unroll
            for (int nt = 0; nt < 4; nt++) {
                bfrag bf = *(const bfrag*)(Bp + (size_t)((((t * 2 + s) * 4 + q) * 256) + wv * 64 + nt * 16 + n16) * 8);
#pragma unroll
                for (int mt = 0; mt < 4; mt++)
                    acc[mt][nt] = __builtin_amdgcn_mfma_f32_16x16x32_bf16(af[mt][s], bf, acc[mt][nt], 0, 0, 0);
            }
        }
    }

    float bv[4];
#pragma unroll
    for (int nt = 0; nt < 4; nt++) bv[nt] = bias[4 * (nt * 16 + n16) + wv];
    int r1 = wv >> 1, r2 = wv & 1;
    int Wo = Win * 2;
    unsigned short* Yb = Y + ((size_t)b * Hin * 2 * Wo + (size_t)(2 * h + r1) * Wo + r2) * 64;
#pragma unroll
    for (int mt = 0; mt < 4; mt++) {
#pragma unroll
        for (int r = 0; r < 4; r++) {
            int m = mt * 16 + q * 4 + r;   // C/D: row = quad*4 + reg
            unsigned short* dst = Yb + (size_t)(2 * (w0 + m)) * 64;
#pragma unroll
            for (int nt = 0; nt < 4; nt++) {
                float v = acc[mt][nt][r] + bv[nt];
                v = fmaxf(v, 0.f);
                dst[nt * 16 + n16] = f2bf(v);
            }
        }
    }
}

// ---------------- final conv as 9-tap implicit GEMM, N=16 (3 real), fp32 NCHW out
__global__ void __launch_bounds__(256)
final_mfma_kernel(const unsigned short* __restrict__ X, const unsigned short* __restrict__ Bp,
                  const float* __restrict__ bias, float* __restrict__ out) {
    int wv = threadIdx.x >> 6, lane = threadIdx.x & 63;
    int q = lane >> 4, n16 = lane & 15;
    int m0 = blockIdx.x * 256 + wv * 64;
    int b = m0 >> 16;
    int rem = m0 & 65535;
    int h = rem >> 8, w0 = rem & 255;
    const unsigned short* Xb = X + (size_t)b * 65536 * 64;

    ffrag acc[4];
#pragma unroll
    for (int i = 0; i < 4; i++) acc[i] = (ffrag)0.f;
    const bfrag zf = (bfrag)(short)0;

    for (int t = 0; t < 9; t++) {
        int dy = t / 3 - 1, dx = t % 3 - 1;
        int hh = h + dy;
        if ((unsigned)hh >= 256u) continue;
        bfrag af[4][2];
#pragma unroll
        for (int mt = 0; mt < 4; mt++) {
            int wp = w0 + mt * 16 + n16 + dx;
            bool ok = (unsigned)wp < 256u;
            const unsigned short* src = Xb + ((size_t)hh * 256 + wp) * 64 + q * 8;
            af[mt][0] = ok ? *(const bfrag*)src : zf;
            af[mt][1] = ok ? *(const bfrag*)(src + 32) : zf;
        }
#pragma unroll
        for (int s = 0; s < 2; s++) {
            bfrag bf = *(const bfrag*)(Bp + (size_t)((((t * 2 + s) * 4 + q) * 16) + n16) * 8);
#pragma unroll
            for (int mt = 0; mt < 4; mt++)
                acc[mt] = __builtin_amdgcn_mfma_f32_16x16x32_bf16(af[mt][s], bf, acc[mt], 0, 0, 0);
        }
    }

    if (n16 < 3) {
        float bj = bias[n16];
        float* ob = out + (((size_t)b * 3 + n16) * 256 + h) * 256;
#pragma unroll
        for (int mt = 0; mt < 4; mt++)
#pragma unroll
            for (int r = 0; r < 4; r++)
                ob[w0 + mt * 16 + q * 4 + r] = acc[mt][r] + bj;
    }
}

extern "C" void kernel_launch(void* const* d_in, const int* in_sizes, int n_in,
                              void* d_out, int out_size, void* d_ws, size_t ws_size,
                              hipStream_t stream) {
    const float* x      = (const float*)d_in[0];
    const float* th     = (const float*)d_in[1];
    const float* proj_w = (const float*)d_in[2];
    const float* proj_b = (const float*)d_in[3];
    const float* cf_w   = (const float*)d_in[4];
    const float* cf_b   = (const float*)d_in[5];
    const float* qw     = (const float*)d_in[6];
    const float* qb     = (const float*)d_in[7];
    const float* kw     = (const float*)d_in[8];
    const float* kb     = (const float*)d_in[9];
    const float* vw     = (const float*)d_in[10];
    const float* vb     = (const float*)d_in[11];
    const float* ow     = (const float*)d_in[12];
    const float* ob     = (const float*)d_in[13];
    const float* l1w    = (const float*)d_in[14];
    const float* l1b    = (const float*)d_in[15];
    const float* l2w    = (const float*)d_in[16];
    const float* l2b    = (const float*)d_in[17];
    const float* up_w   = (const float*)d_in[18];
    const float* up_b   = (const float*)d_in[19];
    const float* cl_w   = (const float*)d_in[20];
    const float* cl_b   = (const float*)d_in[21];

    float* ws   = (float*)d_ws;
    float* feat = ws;                         // 2,097,152 f
    float* tf   = feat + 2097152;             // 39,424 f
    float* kbuf = tf + 39424;                 // 630,784 f
    float* vbuf = kbuf + 630784;              // 630,784 f
    unsigned short* X1  = (unsigned short*)(vbuf + 630784);  // 2,097,152 us
    unsigned short* X2  = X1 + 2097152;       // 8,388,608 us
    unsigned short* X3  = X2 + 8388608;       // 33,554,432 us
    unsigned short* PW1 = X3 + 33554432;      // 147,456 us
    unsigned short* PW2 = PW1 + 147456;       // 147,456 us
    unsigned short* PWF = PW2 + 147456;       // 9,216 us
    unsigned short* PQ  = PWF + 9216;         // 65,536 us
    unsigned short* PO  = PQ + 65536;         // 65,536 us

    hipLaunchKernelGGL(pack_up_kernel, dim3(576, 2), dim3(256), 0, stream, up_w, PW1, PW2);
    hipLaunchKernelGGL(pack_final_kernel, dim3(36), dim3(256), 0, stream, cl_w, PWF);
    hipLaunchKernelGGL(pack_proj_kernel, dim3(256), dim3(256), 0, stream, qw, ow, PQ, PO);
    hipLaunchKernelGGL(text_proj_kernel, dim3(BATCH * LTXT), dim3(64), 0, stream,
                       th, proj_w, proj_b, tf);
    hipLaunchKernelGGL(kv_all_kernel, dim3(16 * BATCH * LTXT), dim3(64), 0, stream,
                       tf, kw, kb, vw, vb, l2w, l2b, kbuf, vbuf);
    hipLaunchKernelGGL(conv_in_kernel, dim3((BATCH * C * HW0) / 256), dim3(256), 0, stream,
                       x, cf_w, cf_b, feat);

    hipLaunchKernelGGL(attn_all_kernel, dim3(BATCH * (HW0 / 64)), dim3(1024), 0, stream,
                       feat, kbuf, vbuf, PQ, PO, qb, ob, l1w, l1b, X1);

    hipLaunchKernelGGL(upconv_mfma_kernel, dim3(BATCH * 64 * 64 / 64), dim3(256), 0, stream,
                       X1, PW1, up_b, X2, 64, 64);
    hipLaunchKernelGGL(upconv_mfma_kernel, dim3(BATCH * 128 * 128 / 64), dim3(256), 0, stream,
                       X2, PW2, up_b + 256, X3, 128, 128);
    hipLaunchKernelGGL(final_mfma_kernel, dim3(BATCH * 256 * 256 / 256), dim3(256), 0, stream,
                       X3, PWF, cl_b, (float*)d_out);
}